// Round 8
// baseline (430.880 us; speedup 1.0000x reference)
//
#include <hip/hip_runtime.h>

typedef unsigned short u16;
typedef unsigned int u32;
typedef __bf16 bf16x8 __attribute__((ext_vector_type(8)));
typedef float f32x4 __attribute__((ext_vector_type(4)));

#define TT 6
#define NTOK (6*40*72)      // 17280 tokens
#define KTOT 373            // keys per frame: 45 win + 148 rolled + 180 pooled
#define NKEYS (TT*KTOT)     // 2238 dense keys
#define NCH2 35             // ceil(2238/64) 64-key chunks
#define SCALE 0.08838834764831845f   // 1/sqrt(128)
#define K_EXP2 0.12751743f           // SCALE * log2(e): exp(s*SCALE) = exp2(s*K_EXP2)

__device__ __forceinline__ float bf2f(u16 u){ u32 x = ((u32)u) << 16; return __builtin_bit_cast(float, x); }
// native RNE f32->bf16 (compiler packs pairs into v_cvt_pk_bf16_f32)
__device__ __forceinline__ u16 f2bf(float f){ return __builtin_bit_cast(u16, (__bf16)f); }

// async global->LDS 16B/lane; LDS dest is wave-uniform base + lane*16 (pass the base)
__device__ __forceinline__ void gload16(const u16* g, u16* l){
  __builtin_amdgcn_global_load_lds(
      (const __attribute__((address_space(1))) void*)g,
      (__attribute__((address_space(3))) void*)l, 16, 0, 0);
}

// ---------------- float32 -> bf16 conversion (x), 4 elems/thread ----------------
__global__ __launch_bounds__(256) void convert_x(const float* __restrict__ src, u16* __restrict__ dst, int n4)
{
  int i = blockIdx.x * 256 + threadIdx.x;
  if (i >= n4) return;
  float4 v = *(const float4*)(src + (size_t)i * 4);
  u16 o[4] = {f2bf(v.x), f2bf(v.y), f2bf(v.z), f2bf(v.w)};
  *(uint2*)(dst + (size_t)i * 4) = *(const uint2*)o;
}

// ---------------- weight transpose (coalesced, LDS-tiled): out[m][n][k] = bf16(W_m[k][n]) ----------------
__global__ __launch_bounds__(256) void transpose_w(
    const float* __restrict__ w0, const float* __restrict__ w1,
    const float* __restrict__ w2, const float* __restrict__ w3, u16* __restrict__ out)
{
  __shared__ float tile[64][65];
  int m = blockIdx.z;
  const float* src = m == 0 ? w0 : (m == 1 ? w1 : (m == 2 ? w2 : w3));
  int kb = blockIdx.x * 64, nb = blockIdx.y * 64;
  int tid = threadIdx.x;
  int tx = tid & 63, ty = tid >> 6;   // 64 x 4
#pragma unroll
  for (int i = 0; i < 16; i++)
    tile[ty + 4*i][tx] = src[(size_t)(kb + ty + 4*i) * 512 + nb + tx];
  __syncthreads();
#pragma unroll
  for (int i = 0; i < 16; i++)
    out[m * 262144 + (size_t)(nb + ty + 4*i) * 512 + kb + tx] = f2bf(tile[tx][ty + 4*i]);
}

// ---------------- FUSED QKV GEMM: stage A once, 3 outputs ----------------
// 128x128 tile, BK=32, gload16 staging, linear LDS + (row&3) source swizzle.
// 48 MFMA/wave per barrier pair (vs 16 in the per-z version); A read from HBM once.
__global__ __launch_bounds__(256) void gemm_qkv(
    const u16* __restrict__ A, const u16* __restrict__ wt,
    const float* __restrict__ bq, const float* __restrict__ bk, const float* __restrict__ bv,
    u16* __restrict__ cq, u16* __restrict__ ck, u16* __restrict__ cv, int M)
{
  __shared__ __align__(16) u16 sA[128*32];
  __shared__ __align__(16) u16 sB[3][128*32];
  int mbase = blockIdx.x * 128, nbase = blockIdx.y * 128;
  int tid = threadIdx.x, lane = tid & 63, wave = tid >> 6;
  int wm = (wave >> 1) * 64, wn = (wave & 1) * 64;
  int quad = lane >> 4, tr = lane & 15;
  int lrow = lane >> 2;
  int seg  = (lane & 3) ^ (lrow & 3);

  const u16* gA[2]; const u16* gB[3][2];
#pragma unroll
  for (int r = 0; r < 2; r++){
    gA[r] = A + (size_t)(mbase + wave*32 + r*16 + lrow) * 512 + seg*8;
#pragma unroll
    for (int z = 0; z < 3; z++)
      gB[z][r] = wt + (size_t)z * 262144 + (size_t)(nbase + wave*32 + r*16 + lrow) * 512 + seg*8;
  }
  u16* lA[2]; u16* lB[3][2];
#pragma unroll
  for (int r = 0; r < 2; r++){
    lA[r] = &sA[(wave*32 + r*16) * 32];
#pragma unroll
    for (int z = 0; z < 3; z++)
      lB[z][r] = &sB[z][(wave*32 + r*16) * 32];
  }

  f32x4 acc[3][4][4];
#pragma unroll
  for (int z = 0; z < 3; z++)
#pragma unroll
    for (int i = 0; i < 4; i++)
#pragma unroll
      for (int j = 0; j < 4; j++){ acc[z][i][j][0]=0.f; acc[z][i][j][1]=0.f; acc[z][i][j][2]=0.f; acc[z][i][j][3]=0.f; }

  int rcol = (quad ^ (tr & 3)) * 8;

  for (int k0 = 0; k0 < 512; k0 += 32){
    if (k0) __syncthreads();
#pragma unroll
    for (int r = 0; r < 2; r++){
      gload16(gA[r] + k0, lA[r]);
#pragma unroll
      for (int z = 0; z < 3; z++)
        gload16(gB[z][r] + k0, lB[z][r]);
    }
    __syncthreads();
    bf16x8 a[4];
#pragma unroll
    for (int i = 0; i < 4; i++) a[i] = *(const bf16x8*)(&sA[(wm + i*16 + tr)*32 + rcol]);
#pragma unroll
    for (int z = 0; z < 3; z++){
      bf16x8 b[4];
#pragma unroll
      for (int j = 0; j < 4; j++) b[j] = *(const bf16x8*)(&sB[z][(wn + j*16 + tr)*32 + rcol]);
#pragma unroll
      for (int i = 0; i < 4; i++)
#pragma unroll
        for (int j = 0; j < 4; j++)
          acc[z][i][j] = __builtin_amdgcn_mfma_f32_16x16x32_bf16(a[i], b[j], acc[z][i][j], 0, 0, 0);
    }
  }

  const float* const biasp[3] = {bq, bk, bv};
  u16* const outp[3] = {cq, ck, cv};
#pragma unroll
  for (int z = 0; z < 3; z++){
    u16* Cout = outp[z];
#pragma unroll
    for (int j = 0; j < 4; j++){
      int col = nbase + wn + j*16 + tr;
      float bv2 = biasp[z][col];
#pragma unroll
      for (int i = 0; i < 4; i++)
#pragma unroll
        for (int r2 = 0; r2 < 4; r2++){
          int row = mbase + wm + i*16 + quad*4 + r2;
          if (row < M)
            Cout[(size_t)row * 512 + col] = f2bf(acc[z][i][j][r2] + bv2);
        }
    }
  }
}

// ---------------- GEMM: C[M][512] = A[M][512] @ W + bias (pool + output passes) ----------------
__global__ __launch_bounds__(256) void gemm_bias(
    const u16* __restrict__ A, const u16* __restrict__ wt,
    const float* __restrict__ b0, const float* __restrict__ b1, const float* __restrict__ b2,
    u16* __restrict__ c0, u16* __restrict__ c1, u16* __restrict__ c2, float* __restrict__ cf,
    int wo0, int wo1, int wo2, int M)
{
  __shared__ __align__(16) u16 sA[128*32];
  __shared__ __align__(16) u16 sB[128*32];
  int z = blockIdx.z;
  const u16* Bt = wt + (size_t)(z == 0 ? wo0 : (z == 1 ? wo1 : wo2)) * 262144;
  const float* bias = z == 0 ? b0 : (z == 1 ? b1 : b2);
  u16* Cout = z == 0 ? c0 : (z == 1 ? c1 : c2);
  int mbase = blockIdx.x * 128, nbase = blockIdx.y * 128;
  int tid = threadIdx.x, lane = tid & 63, wave = tid >> 6;
  int wm = (wave >> 1) * 64, wn = (wave & 1) * 64;
  int quad = lane >> 4, tr = lane & 15;
  int lrow = lane >> 2;                        // row within a 16-row staging group
  int seg  = (lane & 3) ^ (lrow & 3);          // pre-swizzled global 16B segment

  const u16* gA[2]; const u16* gB[2];
#pragma unroll
  for (int r = 0; r < 2; r++){
    gA[r] = A  + (size_t)(mbase + wave*32 + r*16 + lrow) * 512 + seg*8;
    gB[r] = Bt + (size_t)(nbase + wave*32 + r*16 + lrow) * 512 + seg*8;
  }
  u16* lA[2]; u16* lB[2];
#pragma unroll
  for (int r = 0; r < 2; r++){
    lA[r] = &sA[(wave*32 + r*16) * 32];
    lB[r] = &sB[(wave*32 + r*16) * 32];
  }

  f32x4 acc[4][4];
#pragma unroll
  for (int i = 0; i < 4; i++)
#pragma unroll
    for (int j = 0; j < 4; j++){ acc[i][j][0]=0.f; acc[i][j][1]=0.f; acc[i][j][2]=0.f; acc[i][j][3]=0.f; }

  int rcol = (quad ^ (tr & 3)) * 8;            // swizzled read column (u16)

  for (int k0 = 0; k0 < 512; k0 += 32){
    if (k0) __syncthreads();                   // prev MFMA reads done
#pragma unroll
    for (int r = 0; r < 2; r++){
      gload16(gA[r] + k0, lA[r]);
      gload16(gB[r] + k0, lB[r]);
    }
    __syncthreads();                           // staged (vmcnt drained before barrier)
    bf16x8 a[4], b[4];
#pragma unroll
    for (int i = 0; i < 4; i++) a[i] = *(const bf16x8*)(&sA[(wm + i*16 + tr)*32 + rcol]);
#pragma unroll
    for (int j = 0; j < 4; j++) b[j] = *(const bf16x8*)(&sB[(wn + j*16 + tr)*32 + rcol]);
#pragma unroll
    for (int i = 0; i < 4; i++)
#pragma unroll
      for (int j = 0; j < 4; j++)
        acc[i][j] = __builtin_amdgcn_mfma_f32_16x16x32_bf16(a[i], b[j], acc[i][j], 0, 0, 0);
  }

#pragma unroll
  for (int j = 0; j < 4; j++){
    int col = nbase + wn + j*16 + tr;
    float bv = bias[col];
#pragma unroll
    for (int i = 0; i < 4; i++)
#pragma unroll
      for (int r2 = 0; r2 < 4; r2++){
        int row = mbase + wm + i*16 + quad*4 + r2;
        if (row < M){
          float val = acc[i][j][r2] + bv;
          if (cf) cf[(size_t)row * 512 + col] = val;
          else    Cout[(size_t)row * 512 + col] = f2bf(val);
        }
      }
  }
}

// ---------------- depthwise 4x4/4 pool conv: px[1080][512] bf16 ----------------
__global__ __launch_bounds__(256) void pool_conv(
    const float* __restrict__ x, const float* __restrict__ pw,
    const float* __restrict__ pb, u16* __restrict__ px)
{
  int idx = blockIdx.x * 256 + threadIdx.x;
  int c = idx & 511, n = idx >> 9;
  int f = n / 180, rp = n % 180, ph = rp / 18, pwc = rp % 18;
  float acc = pb[c];
#pragma unroll
  for (int i = 0; i < 4; i++)
#pragma unroll
    for (int j = 0; j < 4; j++){
      int hh = ph*4 + i, ww = pwc*4 + j;
      acc += x[((size_t)((f*40 + hh)*72 + ww)) * 512 + c] * pw[(i*4 + j)*512 + c];
    }
  px[idx] = f2bf(acc);
}

// ---------------- window mask + VALID_IND compaction table (parallelized) ----------------
__global__ void prep(const float* __restrict__ masks, int* __restrict__ wmask, int* __restrict__ vi)
{
  int tid = threadIdx.x;   // 512 threads
  if (tid < 64) wmask[tid] = 0;
  __syncthreads();
  if (tid < 384){
    int f = tid / 64, win = tid & 63;
    int wi = win >> 3, wj = win & 7;
    int flag = 0;
    for (int p = 0; p < 45; p++){
      int hh = wi*5 + p/9, ww = wj*9 + p%9;
      if (masks[(f*40 + hh)*72 + ww] > 0.f) flag = 1;
    }
    if (flag) atomicOr(&wmask[win], 1);
  }
  if (tid == 448){
    int cnt = 0;
    for (int e = 0; e < 180; e++){
      int s = e / 45, pos = e % 45, pr = pos / 9, pc = pos % 9;
      bool inval = (s == 0 && pr < 2 && pc < 4) || (s == 1 && pr < 2 && pc >= 5) ||
                   (s == 2 && pr >= 3 && pc < 4) || (s == 3 && pr >= 3 && pc >= 5);
      if (!inval) vi[cnt++] = e;
    }
  }
}

// ---------------- per-window gather table (key -> BYTE offset; <0 => ~off into pool bufs) ----------------
__global__ __launch_bounds__(256) void build_idx(const int* __restrict__ vip, int* __restrict__ idxTab)
{
  int win = blockIdx.x, wi = win >> 3, wj = win & 7;
  for (int i = threadIdx.x; i < NKEYS; i += 256){
    int f = i / KTOT, slot = i - f * KTOT;
    int idx;
    if (slot < 45){
      int hh = wi*5 + slot/9, ww = wj*9 + slot%9;
      idx = ((f*40 + hh)*72 + ww) * 1024;
    } else if (slot < 193){
      int e = vip[slot - 45];
      int s2 = e / 45, pos = e - s2*45, pr = pos/9, pc = pos - pr*9;
      int hh = wi*5 + pr + ((s2 < 2) ? 3 : -3);
      int ww = wj*9 + pc + ((s2 & 1) ? -5 : 5);
      if (hh < 0) hh += 40; else if (hh >= 40) hh -= 40;
      if (ww < 0) ww += 72; else if (ww >= 72) ww -= 72;
      idx = ((f*40 + hh)*72 + ww) * 1024;
    } else {
      idx = ~((f*180 + (slot - 193)) * 1024);
    }
    idxTab[win * 2240 + i] = idx;
  }
}

// ================= DENSE attention: block = (window, head), all 6 frames =================
// 18 m-tiles over 8 waves: own tiles {2w,2w+1}; shared tiles 16,17 split by n-tile.
// SWAPPED QK^T: mfma(K,Q) -> lane holds P for q=tr at CONSECUTIVE keys quad*4+r2 ->
// packed b64 P-stores. V staged as key-pairs (8 b32).
__global__ __launch_bounds__(512) void attn_dense(
    const u16* __restrict__ qb, const u16* __restrict__ kb, const u16* __restrict__ vb,
    const u16* __restrict__ pkb, const u16* __restrict__ pvb,
    const int* __restrict__ wmaskp, const int* __restrict__ idxTab,
    u16* __restrict__ yb)
{
  __shared__ __align__(16) u16 sK[64][136];   // 64-key chunk; 68 dw/row ≡ 4 mod 32: conflict-free b128
  __shared__ __align__(16) u16 sVt[128][72];  // V^T [hd][key]; 36 dw/row ≡ 4 mod 32
  __shared__ __align__(16) u32 sPw[288][36];  // P bf16-pairs, u32 cols (32 data + 4 pad); stride 36 dw
  __shared__ int sIdx[2240];                  // key -> byte offset (>=0: token bufs) or ~byteoff
  __shared__ float sDenX[32];                 // den for tiles 16,17 (cross-wave)

  int win = blockIdx.x, head = blockIdx.y;
  if (!wmaskp[win]) return;                   // local windows handled by attn_local
  int wi = win >> 3, wj = win & 7;
  int tid = threadIdx.x, lane = tid & 63, wave = tid >> 6;
  int quad = lane >> 4, tr = lane & 15;

  if (tid < 32) sDenX[tid] = 0.f;
  {
    const int* g = idxTab + win * 2240;
    for (int i = tid; i < NKEYS; i += 512) sIdx[i] = g[i];
  }

  // ---- Q fragments in registers (loaded once): own tiles 2w,2w+1 + shared tile 16+(w>>2) ----
  int mts[3] = {2*wave, 2*wave + 1, 16 + (wave >> 2)};
  bf16x8 qf[3][4];
#pragma unroll
  for (int im = 0; im < 3; im++){
    int row = mts[im]*16 + tr;
    int f = row / 48, r = row - f*48;
    bool vld = r < 45;
    int hh = wi*5 + r/9, ww = wj*9 + r%9;
    const u16* qp = qb + ((size_t)((f*40 + hh)*72 + ww))*512 + head*128;
#pragma unroll
    for (int kt = 0; kt < 4; kt++){
      uint4 v = make_uint4(0,0,0,0);
      if (vld) v = *(const uint4*)(qp + kt*32 + quad*8);
      qf[im][kt] = __builtin_bit_cast(bf16x8, v);
    }
  }

  f32x4 accv[2][8], accx[2];
#pragma unroll
  for (int m = 0; m < 2; m++)
#pragma unroll
    for (int nt = 0; nt < 8; nt++){ accv[m][nt][0]=0.f; accv[m][nt][1]=0.f; accv[m][nt][2]=0.f; accv[m][nt][3]=0.f; }
  accx[0][0]=0.f; accx[0][1]=0.f; accx[0][2]=0.f; accx[0][3]=0.f;
  accx[1][0]=0.f; accx[1][1]=0.f; accx[1][2]=0.f; accx[1][3]=0.f;
  float dacc[2] = {0.f, 0.f};                 // per-lane den partial for q = (own tile)*16 + tr
  float daccx = 0.f;                          // per-lane den partial for shared tile q = tr

  __syncthreads();   // sIdx ready

  // per-lane gather bases (idx table stores byte offsets)
  int upair = tid & 31, dgv = tid >> 5;       // V: key pair 2*upair, d-group dgv (8 d)
  const char* kb2  = (const char*)kb  + head*256 + (tid & 15)*16;
  const char* pkb2 = (const char*)pkb + head*256 + (tid & 15)*16;
  const char* vb2  = (const char*)vb  + head*256 + dgv*16;
  const char* pvb2 = (const char*)pvb + head*256 + dgv*16;

  // register prefetch of chunk ch:
  // K: key = (tid>>4) + 32r, 16B at dg=(tid&15) | V: keys {2u,2u+1}, 16B each at d=dgv*8
  uint4 pfk[2], pfv[2];
  auto pref = [&](int ch){
#pragma unroll
    for (int r = 0; r < 2; r++){ pfk[r] = make_uint4(0,0,0,0); pfv[r] = make_uint4(0,0,0,0); }
    if (ch < NCH2){
      int base = ch * 64;
#pragma unroll
      for (int r = 0; r < 2; r++){
        int jg = base + (tid >> 4) + 32*r;
        if (jg < NKEYS){
          int off = sIdx[jg];
          pfk[r] = *(const uint4*)(off >= 0 ? kb2 + off : pkb2 + ~off);
        }
      }
#pragma unroll
      for (int r = 0; r < 2; r++){
        int jg = base + 2*upair + r;
        if (jg < NKEYS){
          int off = sIdx[jg];
          pfv[r] = *(const uint4*)(off >= 0 ? vb2 + off : pvb2 + ~off);
        }
      }
    }
  };
  pref(0);

  for (int ch = 0; ch < NCH2; ch++){
    __syncthreads();               // prev PV done; sK/sVt free
#pragma unroll
    for (int r = 0; r < 2; r++)
      *(uint4*)(&sK[(tid >> 4) + 32*r][(tid & 15)*8]) = pfk[r];
    {
      u32 va[4] = {pfv[0].x, pfv[0].y, pfv[0].z, pfv[0].w};
      u32 vbp[4] = {pfv[1].x, pfv[1].y, pfv[1].z, pfv[1].w};
#pragma unroll
      for (int jj = 0; jj < 8; jj++){
        u32 lo = (va[jj >> 1] >> (16*(jj & 1))) & 0xffffu;
        u32 hi = (vbp[jj >> 1] >> (16*(jj & 1))) & 0xffffu;
        ((u32*)&sVt[dgv*8 + jj][0])[upair] = lo | (hi << 16);   // keys 2u,2u+1 packed
      }
    }
    __syncthreads();               // staged
    pref(ch + 1);                  // overlap next gather with compute

    // ---- QK^T (swapped: S^T) + exp + packed P store: 4 n-tiles of 16 keys ----
#pragma unroll
    for (int nt = 0; nt < 4; nt++){
      bf16x8 bk[4];
#pragma unroll
      for (int kt = 0; kt < 4; kt++) bk[kt] = *(const bf16x8*)(&sK[nt*16 + tr][kt*32 + quad*8]);
      int colb = ch*64 + nt*16 + quad*4;      // this lane's first key
#pragma unroll
      for (int m = 0; m < 2; m++){
        f32x4 s = {0.f, 0.f, 0.f, 0.f};
#pragma unroll
        for (int kt = 0; kt < 4; kt++) s = __builtin_amdgcn_mfma_f32_16x16x32_bf16(bk[kt], qf[m][kt], s, 0, 0, 0);
        float p[4];
#pragma unroll
        for (int r2 = 0; r2 < 4; r2++){
          p[r2] = (colb + r2 < NKEYS) ? __builtin_amdgcn_exp2f(s[r2] * K_EXP2) : 0.f;
          dacc[m] += p[r2];
        }
        uint2 w;
        w.x = (u32)f2bf(p[0]) | ((u32)f2bf(p[1]) << 16);
        w.y = (u32)f2bf(p[2]) | ((u32)f2bf(p[3]) << 16);
        *(uint2*)(&sPw[(2*wave + m)*16 + tr][nt*8 + quad*2]) = w;
      }
      if (nt == (wave & 3)){        // shared tile 16+(w>>2): wave handles exactly one n-tile
        f32x4 s = {0.f, 0.f, 0.f, 0.f};
#pragma unroll
        for (int kt = 0; kt < 4; kt++) s = __builtin_amdgcn_mfma_f32_16x16x32_bf16(bk[kt], qf[2][kt], s, 0, 0, 0);
        float p[4];
#pragma unroll
        for (int r2 = 0; r2 < 4; r2++){
          p[r2] = (colb + r2 < NKEYS) ? __builtin_amdgcn_exp2f(s[r2] * K_EXP2) : 0.f;
          daccx += p[r2];
        }
        uint2 w;
        w.x = (u32)f2bf(p[0]) | ((u32)f2bf(p[1]) << 16);
        w.y = (u32)f2bf(p[2]) | ((u32)f2bf(p[3]) << 16);
        *(uint2*)(&sPw[(16 + (wave >> 2))*16 + tr][nt*8 + quad*2]) = w;
      }
    }
    __syncthreads();               // sPw complete (incl. cross-wave tiles 16,17)

    // ---- PV (64 keys = 2 k-steps); a-frags from packed sPw ----
#pragma unroll
    for (int kt2 = 0; kt2 < 2; kt2++){
      bf16x8 a0 = *(const bf16x8*)(&sPw[(2*wave)*16 + tr][kt2*16 + quad*4]);
      bf16x8 a1 = *(const bf16x8*)(&sPw[(2*wave + 1)*16 + tr][kt2*16 + quad*4]);
      bf16x8 ax = *(const bf16x8*)(&sPw[(16 + (wave >> 2))*16 + tr][kt2*16 + quad*4]);
#pragma unroll
      for (int nt = 0; nt < 8; nt++){
        bf16x8 bv = *(const bf16x8*)(&sVt[nt*16 + tr][kt2*32 + quad*8]);
        accv[0][nt] = __builtin_amdgcn_mfma_f32_16x16x32_bf16(a0, bv, accv[0][nt], 0, 0, 0);
        accv[1][nt] = __builtin_amdgcn_mfma_f32_16x16x32_bf16(a1, bv, accv[1][nt], 0, 0, 0);
      }
      int he0 = (wave & 3)*2;
      bf16x8 bx0 = *(const bf16x8*)(&sVt[he0*16 + tr][kt2*32 + quad*8]);
      bf16x8 bx1 = *(const bf16x8*)(&sVt[(he0+1)*16 + tr][kt2*32 + quad*8]);
      accx[0] = __builtin_amdgcn_mfma_f32_16x16x32_bf16(ax, bx0, accx[0], 0, 0, 0);
      accx[1] = __builtin_amdgcn_mfma_f32_16x16x32_bf16(ax, bx1, accx[1], 0, 0, 0);
    }
  }

  // ---- denominators: reduce across quads (q = tr is lane-local) ----
  float dred[2];
#pragma unroll
  for (int m = 0; m < 2; m++){
    float d = dacc[m];
    d += __shfl_xor(d, 16, 64); d += __shfl_xor(d, 32, 64);
    dred[m] = d;                  // full den for q = (2w+m)*16 + tr (all lanes)
  }
  {
    float d = daccx;
    d += __shfl_xor(d, 16, 64); d += __shfl_xor(d, 32, 64);
    if (lane < 16) atomicAdd(&sDenX[(wave >> 2)*16 + lane], d);   // wave's 16-key partial
  }
  __syncthreads();

  // ---- epilogue: own tiles (den redistributed via shfl) ----
#pragma unroll
  for (int m = 0; m < 2; m++){
#pragma unroll
    for (int r2 = 0; r2 < 4; r2++){
      float dinvv = 1.f / __shfl(dred[m], quad*4 + r2, 64);
      int row = (2*wave + m)*16 + quad*4 + r2;
      int f = row / 48, r = row - f*48;
      if (r < 45){
        int hh = wi*5 + r/9, ww = wj*9 + r%9;
        size_t base = ((size_t)((f*40 + hh)*72 + ww))*512 + head*128;
#pragma unroll
        for (int nt = 0; nt < 8; nt++)
          yb[base + nt*16 + tr] = f2bf(accv[m][nt][r2] * dinvv);
      }
    }
  }
  // ---- epilogue: shared tile ----
  {
    int e = 16 + (wave >> 2), he0 = (wave & 3)*2;
#pragma unroll
    for (int r2 = 0; r2 < 4; r2++){
      int row = e*16 + quad*4 + r2;
      int f = row / 48, r = row - f*48;
      if (r < 45){
        float dinvv = 1.f / sDenX[(e - 16)*16 + quad*4 + r2];
        int hh = wi*5 + r/9, ww = wj*9 + r%9;
        size_t base = ((size_t)((f*40 + hh)*72 + ww))*512 + head*128;
        yb[base + he0*16 + tr]       = f2bf(accx[0][r2] * dinvv);
        yb[base + (he0 + 1)*16 + tr] = f2bf(accx[1][r2] * dinvv);
      }
    }
  }
}

// ---------------- LOCAL (unmasked) windows: per-frame 45-key attention ----------------
__device__ __forceinline__ const u16* key_src_local(int slot, int qf, int wi, int wj, int head,
    const u16* __restrict__ tokbuf)
{
  int hh = wi*5 + slot/9, ww = wj*9 + slot%9;
  return tokbuf + ((size_t)((qf*40 + hh)*72 + ww)) * 512 + head * 128;
}

__global__ __launch_bounds__(256) void attn_local(
    const u16* __restrict__ qb, const u16* __restrict__ kb, const u16* __restrict__ vb,
    const int* __restrict__ wmaskp, u16* __restrict__ yb)
{
  __shared__ __align__(16) u16 sQ[48][136];
  __shared__ __align__(16) u16 sK[64][136];
  __shared__ __align__(16) u16 sVt[128][72];
  __shared__ __align__(16) u16 sP[48][72];
  __shared__ float sDen[48];

  int win = blockIdx.x, head = blockIdx.y, qf = blockIdx.z;
  if (wmaskp[win]) return;                    // dense windows handled by attn_dense
  int wi = win >> 3, wj = win & 7;
  int tid = threadIdx.x, lane = tid & 63, wave = tid >> 6;
  int quad = lane >> 4, tr = lane & 15;

  if (tid < 48) sDen[tid] = 0.f;

#pragma unroll
  for (int r = 0; r < 3; r++){
    int u = tid + 256 * r;
    int row = u >> 4, dg = u & 15;
    uint4 val = make_uint4(0,0,0,0);
    if (row < 45){
      int hh = wi*5 + row/9, ww = wj*9 + row%9;
      val = *(const uint4*)(qb + ((size_t)((qf*40 + hh)*72 + ww)) * 512 + head*128 + dg*8);
    }
    *(uint4*)(&sQ[row][dg * 8]) = val;
  }

  const int nkeys = 45;
  f32x4 acc[3][2];
#pragma unroll
  for (int a = 0; a < 3; a++)
#pragma unroll
    for (int b = 0; b < 2; b++){ acc[a][b][0]=0.f; acc[a][b][1]=0.f; acc[a][b][2]=0.f; acc[a][b][3]=0.f; }

  // stage K (coalesced) and V (transposed)
#pragma unroll
  for (int r = 0; r < 4; r++){
    int u = tid + 256 * r;
    int key = u >> 4, dg = u & 15;
    uint4 val = make_uint4(0,0,0,0);
    if (key < nkeys) val = *(const uint4*)(key_src_local(key, qf, wi, wj, head, kb) + dg * 8);
    *(uint4*)(&sK[key][dg * 8]) = val;
  }
#pragma unroll
  for (int r = 0; r < 4; r++){
    int u = tid + 256 * r;
    int key = u & 63, dg = u >> 6;
    uint4 val = make_uint4(0,0,0,0);
    if (key < nkeys) val = *(const uint4*)(key_src_local(key, qf, wi, wj, head, vb) + dg * 8);
    u32 vv[4] = {val.x, val.y, val.z, val.w};
#pragma unroll
    for (int q2 = 0; q2 < 4; q2++){
      sVt[dg*8 + q2*2][key]     = (u16)(vv[q2] & 0xffff);
      sVt[dg*8 + q2*2 + 1][key] = (u16)(vv[q2] >> 16);
    }
  }
  __syncthreads();

#pragma unroll
  for (int mt = 0; mt < 3; mt++){
    f32x4 sacc = {0.f, 0.f, 0.f, 0.f};
#pragma unroll
    for (int kt = 0; kt < 4; kt++){
      bf16x8 a = *(const bf16x8*)(&sQ[mt*16 + tr][kt*32 + quad*8]);
      bf16x8 b = *(const bf16x8*)(&sK[wave*16 + tr][kt*32 + quad*8]);
      sacc = __builtin_amdgcn_mfma_f32_16x16x32_bf16(a, b, sacc, 0, 0, 0);
    }
    int colg = wave * 16 + tr;
    float pr4[4];
#pragma unroll
    for (int r2 = 0; r2 < 4; r2++){
      float p = (colg < nkeys) ? __builtin_amdgcn_exp2f(sacc[r2] * K_EXP2) : 0.f;
      sP[mt*16 + quad*4 + r2][wave*16 + tr] = f2bf(p);
      pr4[r2] = p;
    }
#pragma unroll
    for (int r2 = 0; r2 < 4; r2++){
      float ps = pr4[r2];
      ps += __shfl_xor(ps, 1, 64);
      ps += __shfl_xor(ps, 2, 64);
      ps += __shfl_xor(ps, 4, 64);
      ps += __shfl_xor(ps, 8, 64);
      if (tr == 0) atomicAdd(&sDen[mt*16 + quad*4 + r2], ps);
    }
  }
  __syncthreads();

#pragma unroll
  for (int mt = 0; mt < 3; mt++)
#pragma unroll
    for (int nt = 0; nt < 2; nt++)
#pragma unroll
      for (int kt = 0; kt < 2; kt++){
        bf16x8 a = *(const bf16x8*)(&sP[mt*16 + tr][kt*32 + quad*8]);
        bf16x8 b = *(const bf16x8*)(&sVt[wave*32 + nt*16 + tr][kt*32 + quad*8]);
        acc[mt][nt] = __builtin_amdgcn_mfma_f32_16x16x32_bf16(a, b, acc[mt][nt], 0, 0, 0);
      }
  __syncthreads();

#pragma unroll
  for (int mt = 0; mt < 3; mt++)
#pragma unroll
    for (int r2 = 0; r2 < 4; r2++){
      int row = mt*16 + quad*4 + r2;
      if (row < 45){
        float dinv = 1.0f / sDen[row];
        int hh = wi*5 + row/9, ww = wj*9 + row%9;
        size_t base = ((size_t)((qf*40 + hh)*72 + ww)) * 512 + head * 128;
#pragma unroll
        for (int nt = 0; nt < 2; nt++){
          int col = wave*32 + nt*16 + tr;
          yb[base + col] = f2bf(acc[mt][nt][r2] * dinv);
        }
      }
    }
}

extern "C" void kernel_launch(void* const* d_in, const int* in_sizes, int n_in,
                              void* d_out, int out_size, void* d_ws, size_t ws_size,
                              hipStream_t stream)
{
  const float* x     = (const float*)d_in[0];
  const float* masks = (const float*)d_in[1];
  const float* Wq = (const float*)d_in[2];  const float* bq = (const float*)d_in[3];
  const float* Wk = (const float*)d_in[4];  const float* bk = (const float*)d_in[5];
  const float* Wv = (const float*)d_in[6];  const float* bv = (const float*)d_in[7];
  const float* Wp = (const float*)d_in[8];  const float* bp = (const float*)d_in[9];
  const float* pw = (const float*)d_in[10]; const float* pb = (const float*)d_in[11];
  float* out = (float*)d_out;

  char* ws = (char*)d_ws;
  size_t off = 0;
  auto alloc = [&](size_t bytes) -> char* {
    char* p = ws + off; off += (bytes + 255) & ~(size_t)255; return p;
  };
  u16* wt    = (u16*)alloc((size_t)4 * 512 * 512 * 2);
  u16* xbf   = (u16*)alloc((size_t)NTOK * 512 * 2);
  u16* qbuf  = (u16*)alloc((size_t)NTOK * 512 * 2);
  u16* kbuf  = (u16*)alloc((size_t)NTOK * 512 * 2);
  u16* vbuf  = (u16*)alloc((size_t)NTOK * 512 * 2);
  u16* pxbuf = (u16*)alloc((size_t)1080 * 512 * 2);
  u16* pkbuf = (u16*)alloc((size_t)1080 * 512 * 2);
  u16* pvbuf = (u16*)alloc((size_t)1080 * 512 * 2);
  u16* ybuf  = (u16*)alloc((size_t)NTOK * 512 * 2);
  int* wmaskb = (int*)alloc(64 * 4);
  int* vib    = (int*)alloc(148 * 4);
  int* idxTabb = (int*)alloc((size_t)64 * 2240 * 4);

  convert_x<<<dim3((NTOK*512/4 + 255)/256), 256, 0, stream>>>(x, xbf, NTOK*512/4);
  transpose_w<<<dim3(8, 8, 4), 256, 0, stream>>>(Wq, Wk, Wv, Wp, wt);
  gemm_qkv<<<dim3(135, 4), 256, 0, stream>>>(xbf, wt, bq, bk, bv, qbuf, kbuf, vbuf, NTOK);
  pool_conv<<<dim3(2160), 256, 0, stream>>>(x, pw, pb, pxbuf);
  gemm_bias<<<dim3(9, 4, 2), 256, 0, stream>>>(pxbuf, wt, bk, bv, bv, pkbuf, pvbuf, pvbuf, nullptr, 1, 2, 2, 1080);
  prep<<<dim3(1), 512, 0, stream>>>(masks, wmaskb, vib);
  build_idx<<<dim3(64), 256, 0, stream>>>(vib, idxTabb);
  attn_dense<<<dim3(64, 4), 512, 0, stream>>>(qbuf, kbuf, vbuf, pkbuf, pvbuf, wmaskb, idxTabb, ybuf);
  attn_local<<<dim3(64, 4, 6), 256, 0, stream>>>(qbuf, kbuf, vbuf, wmaskb, ybuf);
  gemm_bias<<<dim3(135, 4, 1), 256, 0, stream>>>(ybuf, wt, bp, bp, bp, nullptr, nullptr, nullptr, out, 3, 3, 3, NTOK);
}

// Round 9
// 357.262 us; speedup vs baseline: 1.2061x; 1.2061x over previous
//
#include <hip/hip_runtime.h>

typedef unsigned short u16;
typedef unsigned int u32;
typedef __bf16 bf16x8 __attribute__((ext_vector_type(8)));
typedef float f32x4 __attribute__((ext_vector_type(4)));

#define TT 6
#define NTOK (6*40*72)      // 17280 tokens
#define NPOOL 1080          // pooled tokens (6 frames x 180)
#define MALL (NTOK + NPOOL) // 18360 rows through the QKV GEMM
#define KTOT 373            // keys per frame: 45 win + 148 rolled + 180 pooled
#define NKEYS (TT*KTOT)     // 2238 dense keys
#define NCH2 35             // ceil(2238/64) 64-key chunks
#define SCALE 0.08838834764831845f   // 1/sqrt(128)
#define K_EXP2 0.12751743f           // SCALE * log2(e): exp(s*SCALE) = exp2(s*K_EXP2)

__device__ __forceinline__ float bf2f(u16 u){ u32 x = ((u32)u) << 16; return __builtin_bit_cast(float, x); }
// native RNE f32->bf16 (compiler packs pairs into v_cvt_pk_bf16_f32)
__device__ __forceinline__ u16 f2bf(float f){ return __builtin_bit_cast(u16, (__bf16)f); }

// async global->LDS 16B/lane; LDS dest is wave-uniform base + lane*16 (pass the base)
__device__ __forceinline__ void gload16(const u16* g, u16* l){
  __builtin_amdgcn_global_load_lds(
      (const __attribute__((address_space(1))) void*)g,
      (__attribute__((address_space(3))) void*)l, 16, 0, 0);
}

// ---------------- float32 -> bf16 conversion (x), 4 elems/thread ----------------
__global__ __launch_bounds__(256) void convert_x(const float* __restrict__ src, u16* __restrict__ dst, int n4)
{
  int i = blockIdx.x * 256 + threadIdx.x;
  if (i >= n4) return;
  float4 v = *(const float4*)(src + (size_t)i * 4);
  u16 o[4] = {f2bf(v.x), f2bf(v.y), f2bf(v.z), f2bf(v.w)};
  *(uint2*)(dst + (size_t)i * 4) = *(const uint2*)o;
}

// ---------------- weight transpose (coalesced, LDS-tiled): out[m][n][k] = bf16(W_m[k][n]) ----------------
__global__ __launch_bounds__(256) void transpose_w(
    const float* __restrict__ w0, const float* __restrict__ w1,
    const float* __restrict__ w2, const float* __restrict__ w3, u16* __restrict__ out)
{
  __shared__ float tile[64][65];
  int m = blockIdx.z;
  const float* src = m == 0 ? w0 : (m == 1 ? w1 : (m == 2 ? w2 : w3));
  int kb = blockIdx.x * 64, nb = blockIdx.y * 64;
  int tid = threadIdx.x;
  int tx = tid & 63, ty = tid >> 6;   // 64 x 4
#pragma unroll
  for (int i = 0; i < 16; i++)
    tile[ty + 4*i][tx] = src[(size_t)(kb + ty + 4*i) * 512 + nb + tx];
  __syncthreads();
#pragma unroll
  for (int i = 0; i < 16; i++)
    out[m * 262144 + (size_t)(nb + ty + 4*i) * 512 + kb + tx] = f2bf(tile[tx][ty + 4*i]);
}

// ---------------- GEMM: C[M][512] = A[M][512] @ W + bias ----------------
// 128x128 tile, BK=32, staging via global_load_lds (16B/lane) into LINEAR [128][32] LDS.
// Global source segment pre-swizzled by (row&3); MFMA reads XOR quad with (tr&3) -> 4-way max.
__global__ __launch_bounds__(256) void gemm_bias(
    const u16* __restrict__ A, const u16* __restrict__ wt,
    const float* __restrict__ b0, const float* __restrict__ b1, const float* __restrict__ b2,
    u16* __restrict__ c0, u16* __restrict__ c1, u16* __restrict__ c2, float* __restrict__ cf,
    int wo0, int wo1, int wo2, int M)
{
  __shared__ __align__(16) u16 sA[128*32];
  __shared__ __align__(16) u16 sB[128*32];
  int z = blockIdx.z;
  const u16* Bt = wt + (size_t)(z == 0 ? wo0 : (z == 1 ? wo1 : wo2)) * 262144;
  const float* bias = z == 0 ? b0 : (z == 1 ? b1 : b2);
  u16* Cout = z == 0 ? c0 : (z == 1 ? c1 : c2);
  int mbase = blockIdx.x * 128, nbase = blockIdx.y * 128;
  int tid = threadIdx.x, lane = tid & 63, wave = tid >> 6;
  int wm = (wave >> 1) * 64, wn = (wave & 1) * 64;
  int quad = lane >> 4, tr = lane & 15;
  int lrow = lane >> 2;                        // row within a 16-row staging group
  int seg  = (lane & 3) ^ (lrow & 3);          // pre-swizzled global 16B segment

  const u16* gA[2]; const u16* gB[2];
#pragma unroll
  for (int r = 0; r < 2; r++){
    gA[r] = A  + (size_t)(mbase + wave*32 + r*16 + lrow) * 512 + seg*8;
    gB[r] = Bt + (size_t)(nbase + wave*32 + r*16 + lrow) * 512 + seg*8;
  }
  u16* lA[2]; u16* lB[2];
#pragma unroll
  for (int r = 0; r < 2; r++){
    lA[r] = &sA[(wave*32 + r*16) * 32];
    lB[r] = &sB[(wave*32 + r*16) * 32];
  }

  f32x4 acc[4][4];
#pragma unroll
  for (int i = 0; i < 4; i++)
#pragma unroll
    for (int j = 0; j < 4; j++){ acc[i][j][0]=0.f; acc[i][j][1]=0.f; acc[i][j][2]=0.f; acc[i][j][3]=0.f; }

  int rcol = (quad ^ (tr & 3)) * 8;            // swizzled read column (u16)

  for (int k0 = 0; k0 < 512; k0 += 32){
    if (k0) __syncthreads();                   // prev MFMA reads done
#pragma unroll
    for (int r = 0; r < 2; r++){
      gload16(gA[r] + k0, lA[r]);
      gload16(gB[r] + k0, lB[r]);
    }
    __syncthreads();                           // staged (vmcnt drained before barrier)
    bf16x8 a[4], b[4];
#pragma unroll
    for (int i = 0; i < 4; i++) a[i] = *(const bf16x8*)(&sA[(wm + i*16 + tr)*32 + rcol]);
#pragma unroll
    for (int j = 0; j < 4; j++) b[j] = *(const bf16x8*)(&sB[(wn + j*16 + tr)*32 + rcol]);
#pragma unroll
    for (int i = 0; i < 4; i++)
#pragma unroll
      for (int j = 0; j < 4; j++)
        acc[i][j] = __builtin_amdgcn_mfma_f32_16x16x32_bf16(a[i], b[j], acc[i][j], 0, 0, 0);
  }

#pragma unroll
  for (int j = 0; j < 4; j++){
    int col = nbase + wn + j*16 + tr;
    float bv = bias[col];
#pragma unroll
    for (int i = 0; i < 4; i++)
#pragma unroll
      for (int r2 = 0; r2 < 4; r2++){
        int row = mbase + wm + i*16 + quad*4 + r2;
        if (row < M){
          float val = acc[i][j][r2] + bv;
          if (cf) cf[(size_t)row * 512 + col] = val;
          else    Cout[(size_t)row * 512 + col] = f2bf(val);
        }
      }
  }
}

// ---------------- depthwise 4x4/4 pool conv: bf16 rows appended at xbf + NTOK*512 ----------------
__global__ __launch_bounds__(256) void pool_conv(
    const float* __restrict__ x, const float* __restrict__ pw,
    const float* __restrict__ pb, u16* __restrict__ px)
{
  int idx = blockIdx.x * 256 + threadIdx.x;
  int c = idx & 511, n = idx >> 9;
  int f = n / 180, rp = n % 180, ph = rp / 18, pwc = rp % 18;
  float acc = pb[c];
#pragma unroll
  for (int i = 0; i < 4; i++)
#pragma unroll
    for (int j = 0; j < 4; j++){
      int hh = ph*4 + i, ww = pwc*4 + j;
      acc += x[((size_t)((f*40 + hh)*72 + ww)) * 512 + c] * pw[(i*4 + j)*512 + c];
    }
  px[idx] = f2bf(acc);
}

// ---------------- per-window: wmask + gather table (merged; vi computed in-block) ----------------
__global__ __launch_bounds__(256) void build_idx(
    const float* __restrict__ masks, int* __restrict__ wmask, int* __restrict__ idxTab)
{
  __shared__ int sVI[148];
  __shared__ int sFlag;
  int win = blockIdx.x, wi = win >> 3, wj = win & 7;
  int tid = threadIdx.x;
  if (tid == 0){
    sFlag = 0;
    int cnt = 0;
    for (int e = 0; e < 180; e++){
      int s = e / 45, pos = e % 45, pr = pos / 9, pc = pos % 9;
      bool inval = (s == 0 && pr < 2 && pc < 4) || (s == 1 && pr < 2 && pc >= 5) ||
                   (s == 2 && pr >= 3 && pc < 4) || (s == 3 && pr >= 3 && pc >= 5);
      if (!inval) sVI[cnt++] = e;
    }
  }
  __syncthreads();
  if (tid < 270){
    int f = tid / 45, p = tid - (tid / 45) * 45;
    int hh = wi*5 + p/9, ww = wj*9 + p%9;
    if (masks[(f*40 + hh)*72 + ww] > 0.f) atomicOr(&sFlag, 1);
  }
  __syncthreads();
  if (tid == 0) wmask[win] = sFlag;

  for (int i = tid; i < NKEYS; i += 256){
    int f = i / KTOT, slot = i - f * KTOT;
    int idx;
    if (slot < 45){
      int hh = wi*5 + slot/9, ww = wj*9 + slot%9;
      idx = ((f*40 + hh)*72 + ww) * 1024;
    } else if (slot < 193){
      int e = sVI[slot - 45];
      int s2 = e / 45, pos = e - s2*45, pr = pos/9, pc = pos - pr*9;
      int hh = wi*5 + pr + ((s2 < 2) ? 3 : -3);
      int ww = wj*9 + pc + ((s2 & 1) ? -5 : 5);
      if (hh < 0) hh += 40; else if (hh >= 40) hh -= 40;
      if (ww < 0) ww += 72; else if (ww >= 72) ww -= 72;
      idx = ((f*40 + hh)*72 + ww) * 1024;
    } else {
      idx = ~((f*180 + (slot - 193)) * 1024);
    }
    idxTab[win * 2240 + i] = idx;
  }
}

// ================= DENSE attention: block = (window, head), all 6 frames =================
// 18 m-tiles over 8 waves: own tiles {2w,2w+1}; shared tiles 16,17 split by n-tile.
// SWAPPED QK^T: mfma(K,Q) -> lane holds P for q=tr at CONSECUTIVE keys quad*4+r2 ->
// packed b64 P-stores. V staged as key-pairs (8 b32).
__global__ __launch_bounds__(512) void attn_dense(
    const u16* __restrict__ qb, const u16* __restrict__ kb, const u16* __restrict__ vb,
    const u16* __restrict__ pkb, const u16* __restrict__ pvb,
    const int* __restrict__ wmaskp, const int* __restrict__ idxTab,
    u16* __restrict__ yb)
{
  __shared__ __align__(16) u16 sK[64][136];   // 64-key chunk; 68 dw/row ≡ 4 mod 32: conflict-free b128
  __shared__ __align__(16) u16 sVt[128][72];  // V^T [hd][key]; 36 dw/row ≡ 4 mod 32
  __shared__ __align__(16) u32 sPw[288][36];  // P bf16-pairs, u32 cols (32 data + 4 pad); stride 36 dw
  __shared__ int sIdx[2240];                  // key -> byte offset (>=0: token bufs) or ~byteoff
  __shared__ float sDenX[32];                 // den for tiles 16,17 (cross-wave)

  int win = blockIdx.x, head = blockIdx.y;
  if (!wmaskp[win]) return;                   // local windows handled by attn_local
  int wi = win >> 3, wj = win & 7;
  int tid = threadIdx.x, lane = tid & 63, wave = tid >> 6;
  int quad = lane >> 4, tr = lane & 15;

  if (tid < 32) sDenX[tid] = 0.f;
  {
    const int* g = idxTab + win * 2240;
    for (int i = tid; i < NKEYS; i += 512) sIdx[i] = g[i];
  }

  // ---- Q fragments in registers (loaded once): own tiles 2w,2w+1 + shared tile 16+(w>>2) ----
  int mts[3] = {2*wave, 2*wave + 1, 16 + (wave >> 2)};
  bf16x8 qf[3][4];
#pragma unroll
  for (int im = 0; im < 3; im++){
    int row = mts[im]*16 + tr;
    int f = row / 48, r = row - f*48;
    bool vld = r < 45;
    int hh = wi*5 + r/9, ww = wj*9 + r%9;
    const u16* qp = qb + ((size_t)((f*40 + hh)*72 + ww))*512 + head*128;
#pragma unroll
    for (int kt = 0; kt < 4; kt++){
      uint4 v = make_uint4(0,0,0,0);
      if (vld) v = *(const uint4*)(qp + kt*32 + quad*8);
      qf[im][kt] = __builtin_bit_cast(bf16x8, v);
    }
  }

  f32x4 accv[2][8], accx[2];
#pragma unroll
  for (int m = 0; m < 2; m++)
#pragma unroll
    for (int nt = 0; nt < 8; nt++){ accv[m][nt][0]=0.f; accv[m][nt][1]=0.f; accv[m][nt][2]=0.f; accv[m][nt][3]=0.f; }
  accx[0][0]=0.f; accx[0][1]=0.f; accx[0][2]=0.f; accx[0][3]=0.f;
  accx[1][0]=0.f; accx[1][1]=0.f; accx[1][2]=0.f; accx[1][3]=0.f;
  float dacc[2] = {0.f, 0.f};                 // per-lane den partial for q = (own tile)*16 + tr
  float daccx = 0.f;                          // per-lane den partial for shared tile q = tr

  __syncthreads();   // sIdx ready

  // per-lane gather bases (idx table stores byte offsets)
  int upair = tid & 31, dgv = tid >> 5;       // V: key pair 2*upair, d-group dgv (8 d)
  const char* kb2  = (const char*)kb  + head*256 + (tid & 15)*16;
  const char* pkb2 = (const char*)pkb + head*256 + (tid & 15)*16;
  const char* vb2  = (const char*)vb  + head*256 + dgv*16;
  const char* pvb2 = (const char*)pvb + head*256 + dgv*16;

  // register prefetch of chunk ch:
  // K: key = (tid>>4) + 32r, 16B at dg=(tid&15) | V: keys {2u,2u+1}, 16B each at d=dgv*8
  uint4 pfk[2], pfv[2];
  auto pref = [&](int ch){
#pragma unroll
    for (int r = 0; r < 2; r++){ pfk[r] = make_uint4(0,0,0,0); pfv[r] = make_uint4(0,0,0,0); }
    if (ch < NCH2){
      int base = ch * 64;
#pragma unroll
      for (int r = 0; r < 2; r++){
        int jg = base + (tid >> 4) + 32*r;
        if (jg < NKEYS){
          int off = sIdx[jg];
          pfk[r] = *(const uint4*)(off >= 0 ? kb2 + off : pkb2 + ~off);
        }
      }
#pragma unroll
      for (int r = 0; r < 2; r++){
        int jg = base + 2*upair + r;
        if (jg < NKEYS){
          int off = sIdx[jg];
          pfv[r] = *(const uint4*)(off >= 0 ? vb2 + off : pvb2 + ~off);
        }
      }
    }
  };
  pref(0);

  for (int ch = 0; ch < NCH2; ch++){
    __syncthreads();               // prev PV done; sK/sVt free
#pragma unroll
    for (int r = 0; r < 2; r++)
      *(uint4*)(&sK[(tid >> 4) + 32*r][(tid & 15)*8]) = pfk[r];
    {
      u32 va[4] = {pfv[0].x, pfv[0].y, pfv[0].z, pfv[0].w};
      u32 vbp[4] = {pfv[1].x, pfv[1].y, pfv[1].z, pfv[1].w};
#pragma unroll
      for (int jj = 0; jj < 8; jj++){
        u32 lo = (va[jj >> 1] >> (16*(jj & 1))) & 0xffffu;
        u32 hi = (vbp[jj >> 1] >> (16*(jj & 1))) & 0xffffu;
        ((u32*)&sVt[dgv*8 + jj][0])[upair] = lo | (hi << 16);   // keys 2u,2u+1 packed
      }
    }
    __syncthreads();               // staged
    pref(ch + 1);                  // overlap next gather with compute

    // ---- QK^T (swapped: S^T) + exp + packed P store: 4 n-tiles of 16 keys ----
#pragma unroll
    for (int nt = 0; nt < 4; nt++){
      bf16x8 bk[4];
#pragma unroll
      for (int kt = 0; kt < 4; kt++) bk[kt] = *(const bf16x8*)(&sK[nt*16 + tr][kt*32 + quad*8]);
      int colb = ch*64 + nt*16 + quad*4;      // this lane's first key
#pragma unroll
      for (int m = 0; m < 2; m++){
        f32x4 s = {0.f, 0.f, 0.f, 0.f};
#pragma unroll
        for (int kt = 0; kt < 4; kt++) s = __builtin_amdgcn_mfma_f32_16x16x32_bf16(bk[kt], qf[m][kt], s, 0, 0, 0);
        float p[4];
#pragma unroll
        for (int r2 = 0; r2 < 4; r2++){
          p[r2] = (colb + r2 < NKEYS) ? __builtin_amdgcn_exp2f(s[r2] * K_EXP2) : 0.f;
          dacc[m] += p[r2];
        }
        uint2 w;
        w.x = (u32)f2bf(p[0]) | ((u32)f2bf(p[1]) << 16);
        w.y = (u32)f2bf(p[2]) | ((u32)f2bf(p[3]) << 16);
        *(uint2*)(&sPw[(2*wave + m)*16 + tr][nt*8 + quad*2]) = w;
      }
      if (nt == (wave & 3)){        // shared tile 16+(w>>2): wave handles exactly one n-tile
        f32x4 s = {0.f, 0.f, 0.f, 0.f};
#pragma unroll
        for (int kt = 0; kt < 4; kt++) s = __builtin_amdgcn_mfma_f32_16x16x32_bf16(bk[kt], qf[2][kt], s, 0, 0, 0);
        float p[4];
#pragma unroll
        for (int r2 = 0; r2 < 4; r2++){
          p[r2] = (colb + r2 < NKEYS) ? __builtin_amdgcn_exp2f(s[r2] * K_EXP2) : 0.f;
          daccx += p[r2];
        }
        uint2 w;
        w.x = (u32)f2bf(p[0]) | ((u32)f2bf(p[1]) << 16);
        w.y = (u32)f2bf(p[2]) | ((u32)f2bf(p[3]) << 16);
        *(uint2*)(&sPw[(16 + (wave >> 2))*16 + tr][nt*8 + quad*2]) = w;
      }
    }
    __syncthreads();               // sPw complete (incl. cross-wave tiles 16,17)

    // ---- PV (64 keys = 2 k-steps); a-frags from packed sPw ----
#pragma unroll
    for (int kt2 = 0; kt2 < 2; kt2++){
      bf16x8 a0 = *(const bf16x8*)(&sPw[(2*wave)*16 + tr][kt2*16 + quad*4]);
      bf16x8 a1 = *(const bf16x8*)(&sPw[(2*wave + 1)*16 + tr][kt2*16 + quad*4]);
      bf16x8 ax = *(const bf16x8*)(&sPw[(16 + (wave >> 2))*16 + tr][kt2*16 + quad*4]);
#pragma unroll
      for (int nt = 0; nt < 8; nt++){
        bf16x8 bv = *(const bf16x8*)(&sVt[nt*16 + tr][kt2*32 + quad*8]);
        accv[0][nt] = __builtin_amdgcn_mfma_f32_16x16x32_bf16(a0, bv, accv[0][nt], 0, 0, 0);
        accv[1][nt] = __builtin_amdgcn_mfma_f32_16x16x32_bf16(a1, bv, accv[1][nt], 0, 0, 0);
      }
      int he0 = (wave & 3)*2;
      bf16x8 bx0 = *(const bf16x8*)(&sVt[he0*16 + tr][kt2*32 + quad*8]);
      bf16x8 bx1 = *(const bf16x8*)(&sVt[(he0+1)*16 + tr][kt2*32 + quad*8]);
      accx[0] = __builtin_amdgcn_mfma_f32_16x16x32_bf16(ax, bx0, accx[0], 0, 0, 0);
      accx[1] = __builtin_amdgcn_mfma_f32_16x16x32_bf16(ax, bx1, accx[1], 0, 0, 0);
    }
  }

  // ---- denominators: reduce across quads (q = tr is lane-local) ----
  float dred[2];
#pragma unroll
  for (int m = 0; m < 2; m++){
    float d = dacc[m];
    d += __shfl_xor(d, 16, 64); d += __shfl_xor(d, 32, 64);
    dred[m] = d;                  // full den for q = (2w+m)*16 + tr (all lanes)
  }
  {
    float d = daccx;
    d += __shfl_xor(d, 16, 64); d += __shfl_xor(d, 32, 64);
    if (lane < 16) atomicAdd(&sDenX[(wave >> 2)*16 + lane], d);   // wave's 16-key partial
  }
  __syncthreads();

  // ---- epilogue: own tiles (den redistributed via shfl) ----
#pragma unroll
  for (int m = 0; m < 2; m++){
#pragma unroll
    for (int r2 = 0; r2 < 4; r2++){
      float dinvv = 1.f / __shfl(dred[m], quad*4 + r2, 64);
      int row = (2*wave + m)*16 + quad*4 + r2;
      int f = row / 48, r = row - f*48;
      if (r < 45){
        int hh = wi*5 + r/9, ww = wj*9 + r%9;
        size_t base = ((size_t)((f*40 + hh)*72 + ww))*512 + head*128;
#pragma unroll
        for (int nt = 0; nt < 8; nt++)
          yb[base + nt*16 + tr] = f2bf(accv[m][nt][r2] * dinvv);
      }
    }
  }
  // ---- epilogue: shared tile ----
  {
    int e = 16 + (wave >> 2), he0 = (wave & 3)*2;
#pragma unroll
    for (int r2 = 0; r2 < 4; r2++){
      int row = e*16 + quad*4 + r2;
      int f = row / 48, r = row - f*48;
      if (r < 45){
        float dinvv = 1.f / sDenX[(e - 16)*16 + quad*4 + r2];
        int hh = wi*5 + r/9, ww = wj*9 + r%9;
        size_t base = ((size_t)((f*40 + hh)*72 + ww))*512 + head*128;
        yb[base + he0*16 + tr]       = f2bf(accx[0][r2] * dinvv);
        yb[base + (he0 + 1)*16 + tr] = f2bf(accx[1][r2] * dinvv);
      }
    }
  }
}

// ---------------- LOCAL (unmasked) windows: per-frame 45-key attention ----------------
__device__ __forceinline__ const u16* key_src_local(int slot, int qf, int wi, int wj, int head,
    const u16* __restrict__ tokbuf)
{
  int hh = wi*5 + slot/9, ww = wj*9 + slot%9;
  return tokbuf + ((size_t)((qf*40 + hh)*72 + ww)) * 512 + head * 128;
}

__global__ __launch_bounds__(256) void attn_local(
    const u16* __restrict__ qb, const u16* __restrict__ kb, const u16* __restrict__ vb,
    const int* __restrict__ wmaskp, u16* __restrict__ yb)
{
  __shared__ __align__(16) u16 sQ[48][136];
  __shared__ __align__(16) u16 sK[64][136];
  __shared__ __align__(16) u16 sVt[128][72];
  __shared__ __align__(16) u16 sP[48][72];
  __shared__ float sDen[48];

  int win = blockIdx.x, head = blockIdx.y, qf = blockIdx.z;
  if (wmaskp[win]) return;                    // dense windows handled by attn_dense
  int wi = win >> 3, wj = win & 7;
  int tid = threadIdx.x, lane = tid & 63, wave = tid >> 6;
  int quad = lane >> 4, tr = lane & 15;

  if (tid < 48) sDen[tid] = 0.f;

#pragma unroll
  for (int r = 0; r < 3; r++){
    int u = tid + 256 * r;
    int row = u >> 4, dg = u & 15;
    uint4 val = make_uint4(0,0,0,0);
    if (row < 45){
      int hh = wi*5 + row/9, ww = wj*9 + row%9;
      val = *(const uint4*)(qb + ((size_t)((qf*40 + hh)*72 + ww)) * 512 + head*128 + dg*8);
    }
    *(uint4*)(&sQ[row][dg * 8]) = val;
  }

  const int nkeys = 45;
  f32x4 acc[3][2];
#pragma unroll
  for (int a = 0; a < 3; a++)
#pragma unroll
    for (int b = 0; b < 2; b++){ acc[a][b][0]=0.f; acc[a][b][1]=0.f; acc[a][b][2]=0.f; acc[a][b][3]=0.f; }

  // stage K (coalesced) and V (transposed)
#pragma unroll
  for (int r = 0; r < 4; r++){
    int u = tid + 256 * r;
    int key = u >> 4, dg = u & 15;
    uint4 val = make_uint4(0,0,0,0);
    if (key < nkeys) val = *(const uint4*)(key_src_local(key, qf, wi, wj, head, kb) + dg * 8);
    *(uint4*)(&sK[key][dg * 8]) = val;
  }
#pragma unroll
  for (int r = 0; r < 4; r++){
    int u = tid + 256 * r;
    int key = u & 63, dg = u >> 6;
    uint4 val = make_uint4(0,0,0,0);
    if (key < nkeys) val = *(const uint4*)(key_src_local(key, qf, wi, wj, head, vb) + dg * 8);
    u32 vv[4] = {val.x, val.y, val.z, val.w};
#pragma unroll
    for (int q2 = 0; q2 < 4; q2++){
      sVt[dg*8 + q2*2][key]     = (u16)(vv[q2] & 0xffff);
      sVt[dg*8 + q2*2 + 1][key] = (u16)(vv[q2] >> 16);
    }
  }
  __syncthreads();

#pragma unroll
  for (int mt = 0; mt < 3; mt++){
    f32x4 sacc = {0.f, 0.f, 0.f, 0.f};
#pragma unroll
    for (int kt = 0; kt < 4; kt++){
      bf16x8 a = *(const bf16x8*)(&sQ[mt*16 + tr][kt*32 + quad*8]);
      bf16x8 b = *(const bf16x8*)(&sK[wave*16 + tr][kt*32 + quad*8]);
      sacc = __builtin_amdgcn_mfma_f32_16x16x32_bf16(a, b, sacc, 0, 0, 0);
    }
    int colg = wave * 16 + tr;
    float pr4[4];
#pragma unroll
    for (int r2 = 0; r2 < 4; r2++){
      float p = (colg < nkeys) ? __builtin_amdgcn_exp2f(sacc[r2] * K_EXP2) : 0.f;
      sP[mt*16 + quad*4 + r2][wave*16 + tr] = f2bf(p);
      pr4[r2] = p;
    }
#pragma unroll
    for (int r2 = 0; r2 < 4; r2++){
      float ps = pr4[r2];
      ps += __shfl_xor(ps, 1, 64);
      ps += __shfl_xor(ps, 2, 64);
      ps += __shfl_xor(ps, 4, 64);
      ps += __shfl_xor(ps, 8, 64);
      if (tr == 0) atomicAdd(&sDen[mt*16 + quad*4 + r2], ps);
    }
  }
  __syncthreads();

#pragma unroll
  for (int mt = 0; mt < 3; mt++)
#pragma unroll
    for (int nt = 0; nt < 2; nt++)
#pragma unroll
      for (int kt = 0; kt < 2; kt++){
        bf16x8 a = *(const bf16x8*)(&sP[mt*16 + tr][kt*32 + quad*8]);
        bf16x8 b = *(const bf16x8*)(&sVt[wave*32 + nt*16 + tr][kt*32 + quad*8]);
        acc[mt][nt] = __builtin_amdgcn_mfma_f32_16x16x32_bf16(a, b, acc[mt][nt], 0, 0, 0);
      }
  __syncthreads();

#pragma unroll
  for (int mt = 0; mt < 3; mt++)
#pragma unroll
    for (int r2 = 0; r2 < 4; r2++){
      int row = mt*16 + quad*4 + r2;
      if (row < 45){
        float dinv = 1.0f / sDen[row];
        int hh = wi*5 + row/9, ww = wj*9 + row%9;
        size_t base = ((size_t)((qf*40 + hh)*72 + ww)) * 512 + head * 128;
#pragma unroll
        for (int nt = 0; nt < 2; nt++){
          int col = wave*32 + nt*16 + tr;
          yb[base + col] = f2bf(acc[mt][nt][r2] * dinv);
        }
      }
    }
}

extern "C" void kernel_launch(void* const* d_in, const int* in_sizes, int n_in,
                              void* d_out, int out_size, void* d_ws, size_t ws_size,
                              hipStream_t stream)
{
  const float* x     = (const float*)d_in[0];
  const float* masks = (const float*)d_in[1];
  const float* Wq = (const float*)d_in[2];  const float* bq = (const float*)d_in[3];
  const float* Wk = (const float*)d_in[4];  const float* bk = (const float*)d_in[5];
  const float* Wv = (const float*)d_in[6];  const float* bv = (const float*)d_in[7];
  const float* Wp = (const float*)d_in[8];  const float* bp = (const float*)d_in[9];
  const float* pw = (const float*)d_in[10]; const float* pb = (const float*)d_in[11];
  float* out = (float*)d_out;

  char* ws = (char*)d_ws;
  size_t off = 0;
  auto alloc = [&](size_t bytes) -> char* {
    char* p = ws + off; off += (bytes + 255) & ~(size_t)255; return p;
  };
  // 18432 rows = 144*128 (token rows + pooled rows + padding for unguarded gload16 reads)
  u16* wt    = (u16*)alloc((size_t)4 * 512 * 512 * 2);
  u16* xbf   = (u16*)alloc((size_t)18432 * 512 * 2);
  u16* qbuf  = (u16*)alloc((size_t)18432 * 512 * 2);
  u16* kbuf  = (u16*)alloc((size_t)18432 * 512 * 2);
  u16* vbuf  = (u16*)alloc((size_t)18432 * 512 * 2);
  u16* ybuf  = (u16*)alloc((size_t)NTOK * 512 * 2);
  int* wmaskb = (int*)alloc(64 * 4);
  int* idxTabb = (int*)alloc((size_t)64 * 2240 * 4);

  u16* pkbuf = kbuf + (size_t)NTOK * 512;   // pooled K/V are tails of kbuf/vbuf
  u16* pvbuf = vbuf + (size_t)NTOK * 512;

  convert_x<<<dim3((NTOK*512/4 + 255)/256), 256, 0, stream>>>(x, xbf, NTOK*512/4);
  pool_conv<<<dim3(2160), 256, 0, stream>>>(x, pw, pb, xbf + (size_t)NTOK * 512);
  transpose_w<<<dim3(8, 8, 4), 256, 0, stream>>>(Wq, Wk, Wv, Wp, wt);
  gemm_bias<<<dim3(144, 4, 3), 256, 0, stream>>>(xbf, wt, bq, bk, bv, qbuf, kbuf, vbuf, nullptr, 0, 1, 2, MALL);
  build_idx<<<dim3(64), 256, 0, stream>>>(masks, wmaskb, idxTabb);
  attn_dense<<<dim3(64, 4), 512, 0, stream>>>(qbuf, kbuf, vbuf, pkbuf, pvbuf, wmaskb, idxTabb, ybuf);
  attn_local<<<dim3(64, 4, 6), 256, 0, stream>>>(qbuf, kbuf, vbuf, wmaskb, ybuf);
  gemm_bias<<<dim3(135, 4, 1), 256, 0, stream>>>(ybuf, wt, bp, bp, bp, nullptr, nullptr, nullptr, out, 3, 3, 3, NTOK);
}

// Round 10
// 329.227 us; speedup vs baseline: 1.3088x; 1.0852x over previous
//
#include <hip/hip_runtime.h>

typedef unsigned short u16;
typedef unsigned int u32;
typedef __bf16 bf16x8 __attribute__((ext_vector_type(8)));
typedef float f32x4 __attribute__((ext_vector_type(4)));

#define TT 6
#define NTOK (6*40*72)      // 17280 tokens
#define NPOOL 1080          // pooled tokens (6 frames x 180)
#define MALL (NTOK + NPOOL) // 18360 rows through the QKV GEMM
#define KTOT 373            // keys per frame: 45 win + 148 rolled + 180 pooled
#define NKEYS (TT*KTOT)     // 2238 dense keys
#define NCH2 35             // ceil(2238/64) 64-key chunks
#define SCALE 0.08838834764831845f   // 1/sqrt(128)
#define K_EXP2 0.12751743f           // SCALE * log2(e): exp(s*SCALE) = exp2(s*K_EXP2)

__device__ __forceinline__ float bf2f(u16 u){ u32 x = ((u32)u) << 16; return __builtin_bit_cast(float, x); }
// native RNE f32->bf16 (compiler packs pairs into v_cvt_pk_bf16_f32)
__device__ __forceinline__ u16 f2bf(float f){ return __builtin_bit_cast(u16, (__bf16)f); }

// async global->LDS 16B/lane; LDS dest is wave-uniform base + lane*16 (pass the base)
__device__ __forceinline__ void gload16(const u16* g, u16* l){
  __builtin_amdgcn_global_load_lds(
      (const __attribute__((address_space(1))) void*)g,
      (__attribute__((address_space(3))) void*)l, 16, 0, 0);
}

// ---------------- MERGED PREP: convert_x | pool_conv | transpose_w | build_idx ----------------
// blocks [0,8640): convert x -> bf16 (4 elems/thread, exact cover)
// blocks [8640,10800): depthwise 4x4/4 pool conv -> bf16 rows appended at xbf+NTOK*512
// blocks [10800,11056): weight transpose (LDS-tiled)
// blocks [11056,11120): per-window wmask + gather table
__global__ __launch_bounds__(256) void prep_all(
    const float* __restrict__ x, const float* __restrict__ masks,
    const float* __restrict__ w0, const float* __restrict__ w1,
    const float* __restrict__ w2, const float* __restrict__ w3,
    const float* __restrict__ pw, const float* __restrict__ pb,
    u16* __restrict__ xbf, u16* __restrict__ wt,
    int* __restrict__ wmask, int* __restrict__ idxTab)
{
  __shared__ __align__(16) float tile[64][65];
  int b = blockIdx.x, tid = threadIdx.x;

  if (b < 8640){
    // ---- convert_x ----
    int i = b * 256 + tid;                     // 8640*256*4 == NTOK*512 exactly
    float4 v = *(const float4*)(x + (size_t)i * 4);
    u16 o[4] = {f2bf(v.x), f2bf(v.y), f2bf(v.z), f2bf(v.w)};
    *(uint2*)(xbf + (size_t)i * 4) = *(const uint2*)o;
  } else if (b < 10800){
    // ---- pool_conv ----
    int idx = (b - 8640) * 256 + tid;          // 2160*256 == 1080*512 exactly
    int c = idx & 511, n = idx >> 9;
    int f = n / 180, rp = n % 180, ph = rp / 18, pwc = rp % 18;
    float acc = pb[c];
#pragma unroll
    for (int i = 0; i < 4; i++)
#pragma unroll
      for (int j = 0; j < 4; j++){
        int hh = ph*4 + i, ww = pwc*4 + j;
        acc += x[((size_t)((f*40 + hh)*72 + ww)) * 512 + c] * pw[(i*4 + j)*512 + c];
      }
    xbf[(size_t)NTOK * 512 + idx] = f2bf(acc);
  } else if (b < 11056){
    // ---- transpose_w ----
    int idx = b - 10800;
    int m = idx >> 6, r = idx & 63;
    int kb = (r >> 3) * 64, nb = (r & 7) * 64;
    const float* src = m == 0 ? w0 : (m == 1 ? w1 : (m == 2 ? w2 : w3));
    int tx = tid & 63, ty = tid >> 6;          // 64 x 4
#pragma unroll
    for (int i = 0; i < 16; i++)
      tile[ty + 4*i][tx] = src[(size_t)(kb + ty + 4*i) * 512 + nb + tx];
    __syncthreads();
#pragma unroll
    for (int i = 0; i < 16; i++)
      wt[m * 262144 + (size_t)(nb + ty + 4*i) * 512 + kb + tx] = f2bf(tile[tx][ty + 4*i]);
  } else {
    // ---- build_idx (wmask + gather table; VALID_IND computed in-block) ----
    int* sVI = (int*)&tile[0][0];
    int* sFlag = sVI + 160;
    int win = b - 11056, wi = win >> 3, wj = win & 7;
    if (tid == 0){
      sFlag[0] = 0;
      int cnt = 0;
      for (int e = 0; e < 180; e++){
        int s = e / 45, pos = e % 45, pr = pos / 9, pc = pos % 9;
        bool inval = (s == 0 && pr < 2 && pc < 4) || (s == 1 && pr < 2 && pc >= 5) ||
                     (s == 2 && pr >= 3 && pc < 4) || (s == 3 && pr >= 3 && pc >= 5);
        if (!inval) sVI[cnt++] = e;
      }
    }
    __syncthreads();
    if (tid < 270){
      int f = tid / 45, p = tid - (tid / 45) * 45;
      int hh = wi*5 + p/9, ww = wj*9 + p%9;
      if (masks[(f*40 + hh)*72 + ww] > 0.f) atomicOr(sFlag, 1);
    }
    __syncthreads();
    if (tid == 0) wmask[win] = sFlag[0];

    for (int i = tid; i < NKEYS; i += 256){
      int f = i / KTOT, slot = i - f * KTOT;
      int idx;
      if (slot < 45){
        int hh = wi*5 + slot/9, ww = wj*9 + slot%9;
        idx = ((f*40 + hh)*72 + ww) * 1024;
      } else if (slot < 193){
        int e = sVI[slot - 45];
        int s2 = e / 45, pos = e - s2*45, pr = pos/9, pc = pos - pr*9;
        int hh = wi*5 + pr + ((s2 < 2) ? 3 : -3);
        int ww = wj*9 + pc + ((s2 & 1) ? -5 : 5);
        if (hh < 0) hh += 40; else if (hh >= 40) hh -= 40;
        if (ww < 0) ww += 72; else if (ww >= 72) ww -= 72;
        idx = ((f*40 + hh)*72 + ww) * 1024;
      } else {
        idx = ~((f*180 + (slot - 193)) * 1024);
      }
      idxTab[win * 2240 + i] = idx;
    }
  }
}

// ---------------- GEMM: C[M][512] = A[M][512] @ W + bias ----------------
// 128x128 tile, BK=32, staging via global_load_lds (16B/lane) into LINEAR [128][32] LDS.
// Global source segment pre-swizzled by (row&3); MFMA reads XOR quad with (tr&3) -> 4-way max.
__global__ __launch_bounds__(256) void gemm_bias(
    const u16* __restrict__ A, const u16* __restrict__ wt,
    const float* __restrict__ b0, const float* __restrict__ b1, const float* __restrict__ b2,
    u16* __restrict__ c0, u16* __restrict__ c1, u16* __restrict__ c2, float* __restrict__ cf,
    int wo0, int wo1, int wo2, int M)
{
  __shared__ __align__(16) u16 sA[128*32];
  __shared__ __align__(16) u16 sB[128*32];
  int z = blockIdx.z;
  const u16* Bt = wt + (size_t)(z == 0 ? wo0 : (z == 1 ? wo1 : wo2)) * 262144;
  const float* bias = z == 0 ? b0 : (z == 1 ? b1 : b2);
  u16* Cout = z == 0 ? c0 : (z == 1 ? c1 : c2);
  int mbase = blockIdx.x * 128, nbase = blockIdx.y * 128;
  int tid = threadIdx.x, lane = tid & 63, wave = tid >> 6;
  int wm = (wave >> 1) * 64, wn = (wave & 1) * 64;
  int quad = lane >> 4, tr = lane & 15;
  int lrow = lane >> 2;                        // row within a 16-row staging group
  int seg  = (lane & 3) ^ (lrow & 3);          // pre-swizzled global 16B segment

  const u16* gA[2]; const u16* gB[2];
#pragma unroll
  for (int r = 0; r < 2; r++){
    gA[r] = A  + (size_t)(mbase + wave*32 + r*16 + lrow) * 512 + seg*8;
    gB[r] = Bt + (size_t)(nbase + wave*32 + r*16 + lrow) * 512 + seg*8;
  }
  u16* lA[2]; u16* lB[2];
#pragma unroll
  for (int r = 0; r < 2; r++){
    lA[r] = &sA[(wave*32 + r*16) * 32];
    lB[r] = &sB[(wave*32 + r*16) * 32];
  }

  f32x4 acc[4][4];
#pragma unroll
  for (int i = 0; i < 4; i++)
#pragma unroll
    for (int j = 0; j < 4; j++){ acc[i][j][0]=0.f; acc[i][j][1]=0.f; acc[i][j][2]=0.f; acc[i][j][3]=0.f; }

  int rcol = (quad ^ (tr & 3)) * 8;            // swizzled read column (u16)

  for (int k0 = 0; k0 < 512; k0 += 32){
    if (k0) __syncthreads();                   // prev MFMA reads done
#pragma unroll
    for (int r = 0; r < 2; r++){
      gload16(gA[r] + k0, lA[r]);
      gload16(gB[r] + k0, lB[r]);
    }
    __syncthreads();                           // staged (vmcnt drained before barrier)
    bf16x8 a[4], b[4];
#pragma unroll
    for (int i = 0; i < 4; i++) a[i] = *(const bf16x8*)(&sA[(wm + i*16 + tr)*32 + rcol]);
#pragma unroll
    for (int j = 0; j < 4; j++) b[j] = *(const bf16x8*)(&sB[(wn + j*16 + tr)*32 + rcol]);
#pragma unroll
    for (int i = 0; i < 4; i++)
#pragma unroll
      for (int j = 0; j < 4; j++)
        acc[i][j] = __builtin_amdgcn_mfma_f32_16x16x32_bf16(a[i], b[j], acc[i][j], 0, 0, 0);
  }

#pragma unroll
  for (int j = 0; j < 4; j++){
    int col = nbase + wn + j*16 + tr;
    float bv = bias[col];
#pragma unroll
    for (int i = 0; i < 4; i++)
#pragma unroll
      for (int r2 = 0; r2 < 4; r2++){
        int row = mbase + wm + i*16 + quad*4 + r2;
        if (row < M){
          float val = acc[i][j][r2] + bv;
          if (cf) cf[(size_t)row * 512 + col] = val;
          else    Cout[(size_t)row * 512 + col] = f2bf(val);
        }
      }
  }
}

// ---------------- local-window key address helper ----------------
__device__ __forceinline__ const u16* key_src_local(int slot, int qf, int wi, int wj, int head,
    const u16* __restrict__ tokbuf)
{
  int hh = wi*5 + slot/9, ww = wj*9 + slot%9;
  return tokbuf + ((size_t)((qf*40 + hh)*72 + ww)) * 512 + head * 128;
}

// ================= MERGED attention: block = (window, head), 512 threads =================
// Dense windows: round-7/9 proven body (swapped QK^T, packed P, 64-key chunks).
// Local windows: per-frame 45-key attention, 2 frames concurrently (waves 0-3 | 4-7,
// disjoint LDS slabs, identical barrier sequence). Local blocks fill CUs idle during
// the dense blocks' execution -> attn_local dispatch eliminated.
__global__ __launch_bounds__(512) void attn(
    const u16* __restrict__ qb, const u16* __restrict__ kb, const u16* __restrict__ vb,
    const u16* __restrict__ pkb, const u16* __restrict__ pvb,
    const int* __restrict__ wmaskp, const int* __restrict__ idxTab,
    u16* __restrict__ yb)
{
  __shared__ __align__(16) char smem[112000];
  int win = blockIdx.x, head = blockIdx.y;
  int wi = win >> 3, wj = win & 7;
  int tid = threadIdx.x, lane = tid & 63, wave = tid >> 6;
  int quad = lane >> 4, tr = lane & 15;

  if (wmaskp[win]){
    // =============== DENSE path (LDS: 86400 B) ===============
    u16 (*sK)[136] = (u16(*)[136])smem;            // 64x136 u16
    u16 (*sVt)[72] = (u16(*)[72])(smem + 17408);   // 128x72 u16
    u32 (*sPw)[36] = (u32(*)[36])(smem + 35840);   // 288x36 u32
    int*  sIdx     = (int*)(smem + 77312);         // 2240
    float* sDenX   = (float*)(smem + 86272);       // 32

    if (tid < 32) sDenX[tid] = 0.f;
    {
      const int* g = idxTab + win * 2240;
      for (int i = tid; i < NKEYS; i += 512) sIdx[i] = g[i];
    }

    // ---- Q fragments in registers: own tiles 2w,2w+1 + shared tile 16+(w>>2) ----
    int mts[3] = {2*wave, 2*wave + 1, 16 + (wave >> 2)};
    bf16x8 qf[3][4];
#pragma unroll
    for (int im = 0; im < 3; im++){
      int row = mts[im]*16 + tr;
      int f = row / 48, r = row - f*48;
      bool vld = r < 45;
      int hh = wi*5 + r/9, ww = wj*9 + r%9;
      const u16* qp = qb + ((size_t)((f*40 + hh)*72 + ww))*512 + head*128;
#pragma unroll
      for (int kt = 0; kt < 4; kt++){
        uint4 v = make_uint4(0,0,0,0);
        if (vld) v = *(const uint4*)(qp + kt*32 + quad*8);
        qf[im][kt] = __builtin_bit_cast(bf16x8, v);
      }
    }

    f32x4 accv[2][8], accx[2];
#pragma unroll
    for (int m = 0; m < 2; m++)
#pragma unroll
      for (int nt = 0; nt < 8; nt++){ accv[m][nt][0]=0.f; accv[m][nt][1]=0.f; accv[m][nt][2]=0.f; accv[m][nt][3]=0.f; }
    accx[0][0]=0.f; accx[0][1]=0.f; accx[0][2]=0.f; accx[0][3]=0.f;
    accx[1][0]=0.f; accx[1][1]=0.f; accx[1][2]=0.f; accx[1][3]=0.f;
    float dacc[2] = {0.f, 0.f};
    float daccx = 0.f;

    __syncthreads();   // sIdx ready

    int upair = tid & 31, dgv = tid >> 5;
    const char* kb2  = (const char*)kb  + head*256 + (tid & 15)*16;
    const char* pkb2 = (const char*)pkb + head*256 + (tid & 15)*16;
    const char* vb2  = (const char*)vb  + head*256 + dgv*16;
    const char* pvb2 = (const char*)pvb + head*256 + dgv*16;

    uint4 pfk[2], pfv[2];
    auto pref = [&](int ch){
#pragma unroll
      for (int r = 0; r < 2; r++){ pfk[r] = make_uint4(0,0,0,0); pfv[r] = make_uint4(0,0,0,0); }
      if (ch < NCH2){
        int base = ch * 64;
#pragma unroll
        for (int r = 0; r < 2; r++){
          int jg = base + (tid >> 4) + 32*r;
          if (jg < NKEYS){
            int off = sIdx[jg];
            pfk[r] = *(const uint4*)(off >= 0 ? kb2 + off : pkb2 + ~off);
          }
        }
#pragma unroll
        for (int r = 0; r < 2; r++){
          int jg = base + 2*upair + r;
          if (jg < NKEYS){
            int off = sIdx[jg];
            pfv[r] = *(const uint4*)(off >= 0 ? vb2 + off : pvb2 + ~off);
          }
        }
      }
    };
    pref(0);

    for (int ch = 0; ch < NCH2; ch++){
      __syncthreads();               // prev PV done; sK/sVt free
#pragma unroll
      for (int r = 0; r < 2; r++)
        *(uint4*)(&sK[(tid >> 4) + 32*r][(tid & 15)*8]) = pfk[r];
      {
        u32 va[4] = {pfv[0].x, pfv[0].y, pfv[0].z, pfv[0].w};
        u32 vbp[4] = {pfv[1].x, pfv[1].y, pfv[1].z, pfv[1].w};
#pragma unroll
        for (int jj = 0; jj < 8; jj++){
          u32 lo = (va[jj >> 1] >> (16*(jj & 1))) & 0xffffu;
          u32 hi = (vbp[jj >> 1] >> (16*(jj & 1))) & 0xffffu;
          ((u32*)&sVt[dgv*8 + jj][0])[upair] = lo | (hi << 16);
        }
      }
      __syncthreads();               // staged
      pref(ch + 1);                  // overlap next gather with compute

      // ---- QK^T (swapped: S^T) + exp + packed P store ----
#pragma unroll
      for (int nt = 0; nt < 4; nt++){
        bf16x8 bk[4];
#pragma unroll
        for (int kt = 0; kt < 4; kt++) bk[kt] = *(const bf16x8*)(&sK[nt*16 + tr][kt*32 + quad*8]);
        int colb = ch*64 + nt*16 + quad*4;
#pragma unroll
        for (int m = 0; m < 2; m++){
          f32x4 s = {0.f, 0.f, 0.f, 0.f};
#pragma unroll
          for (int kt = 0; kt < 4; kt++) s = __builtin_amdgcn_mfma_f32_16x16x32_bf16(bk[kt], qf[m][kt], s, 0, 0, 0);
          float p[4];
#pragma unroll
          for (int r2 = 0; r2 < 4; r2++){
            p[r2] = (colb + r2 < NKEYS) ? __builtin_amdgcn_exp2f(s[r2] * K_EXP2) : 0.f;
            dacc[m] += p[r2];
          }
          uint2 w;
          w.x = (u32)f2bf(p[0]) | ((u32)f2bf(p[1]) << 16);
          w.y = (u32)f2bf(p[2]) | ((u32)f2bf(p[3]) << 16);
          *(uint2*)(&sPw[(2*wave + m)*16 + tr][nt*8 + quad*2]) = w;
        }
        if (nt == (wave & 3)){
          f32x4 s = {0.f, 0.f, 0.f, 0.f};
#pragma unroll
          for (int kt = 0; kt < 4; kt++) s = __builtin_amdgcn_mfma_f32_16x16x32_bf16(bk[kt], qf[2][kt], s, 0, 0, 0);
          float p[4];
#pragma unroll
          for (int r2 = 0; r2 < 4; r2++){
            p[r2] = (colb + r2 < NKEYS) ? __builtin_amdgcn_exp2f(s[r2] * K_EXP2) : 0.f;
            daccx += p[r2];
          }
          uint2 w;
          w.x = (u32)f2bf(p[0]) | ((u32)f2bf(p[1]) << 16);
          w.y = (u32)f2bf(p[2]) | ((u32)f2bf(p[3]) << 16);
          *(uint2*)(&sPw[(16 + (wave >> 2))*16 + tr][nt*8 + quad*2]) = w;
        }
      }
      __syncthreads();               // sPw complete

      // ---- PV (64 keys = 2 k-steps) ----
#pragma unroll
      for (int kt2 = 0; kt2 < 2; kt2++){
        bf16x8 a0 = *(const bf16x8*)(&sPw[(2*wave)*16 + tr][kt2*16 + quad*4]);
        bf16x8 a1 = *(const bf16x8*)(&sPw[(2*wave + 1)*16 + tr][kt2*16 + quad*4]);
        bf16x8 ax = *(const bf16x8*)(&sPw[(16 + (wave >> 2))*16 + tr][kt2*16 + quad*4]);
#pragma unroll
        for (int nt = 0; nt < 8; nt++){
          bf16x8 bv = *(const bf16x8*)(&sVt[nt*16 + tr][kt2*32 + quad*8]);
          accv[0][nt] = __builtin_amdgcn_mfma_f32_16x16x32_bf16(a0, bv, accv[0][nt], 0, 0, 0);
          accv[1][nt] = __builtin_amdgcn_mfma_f32_16x16x32_bf16(a1, bv, accv[1][nt], 0, 0, 0);
        }
        int he0 = (wave & 3)*2;
        bf16x8 bx0 = *(const bf16x8*)(&sVt[he0*16 + tr][kt2*32 + quad*8]);
        bf16x8 bx1 = *(const bf16x8*)(&sVt[(he0+1)*16 + tr][kt2*32 + quad*8]);
        accx[0] = __builtin_amdgcn_mfma_f32_16x16x32_bf16(ax, bx0, accx[0], 0, 0, 0);
        accx[1] = __builtin_amdgcn_mfma_f32_16x16x32_bf16(ax, bx1, accx[1], 0, 0, 0);
      }
    }

    // ---- denominators ----
    float dred[2];
#pragma unroll
    for (int m = 0; m < 2; m++){
      float d = dacc[m];
      d += __shfl_xor(d, 16, 64); d += __shfl_xor(d, 32, 64);
      dred[m] = d;
    }
    {
      float d = daccx;
      d += __shfl_xor(d, 16, 64); d += __shfl_xor(d, 32, 64);
      if (lane < 16) atomicAdd(&sDenX[(wave >> 2)*16 + lane], d);
    }
    __syncthreads();

    // ---- epilogue: own tiles ----
#pragma unroll
    for (int m = 0; m < 2; m++){
#pragma unroll
      for (int r2 = 0; r2 < 4; r2++){
        float dinvv = 1.f / __shfl(dred[m], quad*4 + r2, 64);
        int row = (2*wave + m)*16 + quad*4 + r2;
        int f = row / 48, r = row - f*48;
        if (r < 45){
          int hh = wi*5 + r/9, ww = wj*9 + r%9;
          size_t base = ((size_t)((f*40 + hh)*72 + ww))*512 + head*128;
#pragma unroll
          for (int nt = 0; nt < 8; nt++)
            yb[base + nt*16 + tr] = f2bf(accv[m][nt][r2] * dinvv);
        }
      }
    }
    // ---- epilogue: shared tile ----
    {
      int e = 16 + (wave >> 2), he0 = (wave & 3)*2;
#pragma unroll
      for (int r2 = 0; r2 < 4; r2++){
        int row = e*16 + quad*4 + r2;
        int f = row / 48, r = row - f*48;
        if (r < 45){
          float dinvv = 1.f / sDenX[(e - 16)*16 + quad*4 + r2];
          int hh = wi*5 + r/9, ww = wj*9 + r%9;
          size_t base = ((size_t)((f*40 + hh)*72 + ww))*512 + head*128;
          yb[base + he0*16 + tr]       = f2bf(accx[0][r2] * dinvv);
          yb[base + (he0 + 1)*16 + tr] = f2bf(accx[1][r2] * dinvv);
        }
      }
    }
  } else {
    // =============== LOCAL path: 2 frames concurrently (56000 B LDS per half) ===============
    int half = wave >> 2, lwave = wave & 3, ltid = tid & 255;
    char* base = smem + half * 56000;
    u16 (*sQ)[136]  = (u16(*)[136])base;            // 48x136
    u16 (*sK)[136]  = (u16(*)[136])(base + 13056);  // 64x136
    u16 (*sVt)[72]  = (u16(*)[72])(base + 30464);   // 128x72
    u16 (*sP)[72]   = (u16(*)[72])(base + 48896);   // 48x72
    float* sDen     = (float*)(base + 55808);       // 48
    const int nkeys = 45;

    for (int it = 0; it < 3; it++){
      int qf = it*2 + half;
      if (it) __syncthreads();                 // prev epilogue done before re-staging
      if (ltid < 48) sDen[ltid] = 0.f;

      // stage Q
#pragma unroll
      for (int r = 0; r < 3; r++){
        int u = ltid + 256 * r;
        int row = u >> 4, dg = u & 15;
        uint4 val = make_uint4(0,0,0,0);
        if (row < 45){
          int hh = wi*5 + row/9, ww = wj*9 + row%9;
          val = *(const uint4*)(qb + ((size_t)((qf*40 + hh)*72 + ww)) * 512 + head*128 + dg*8);
        }
        *(uint4*)(&sQ[row][dg * 8]) = val;
      }

      f32x4 acc[3][2];
#pragma unroll
      for (int a = 0; a < 3; a++)
#pragma unroll
        for (int b2 = 0; b2 < 2; b2++){ acc[a][b2][0]=0.f; acc[a][b2][1]=0.f; acc[a][b2][2]=0.f; acc[a][b2][3]=0.f; }

      // stage K (coalesced) and V (transposed)
#pragma unroll
      for (int r = 0; r < 4; r++){
        int u = ltid + 256 * r;
        int key = u >> 4, dg = u & 15;
        uint4 val = make_uint4(0,0,0,0);
        if (key < nkeys) val = *(const uint4*)(key_src_local(key, qf, wi, wj, head, kb) + dg * 8);
        *(uint4*)(&sK[key][dg * 8]) = val;
      }
#pragma unroll
      for (int r = 0; r < 4; r++){
        int u = ltid + 256 * r;
        int key = u & 63, dg = u >> 6;
        uint4 val = make_uint4(0,0,0,0);
        if (key < nkeys) val = *(const uint4*)(key_src_local(key, qf, wi, wj, head, vb) + dg * 8);
        u32 vv[4] = {val.x, val.y, val.z, val.w};
#pragma unroll
        for (int q2 = 0; q2 < 4; q2++){
          sVt[dg*8 + q2*2][key]     = (u16)(vv[q2] & 0xffff);
          sVt[dg*8 + q2*2 + 1][key] = (u16)(vv[q2] >> 16);
        }
      }
      __syncthreads();

#pragma unroll
      for (int mt = 0; mt < 3; mt++){
        f32x4 sacc = {0.f, 0.f, 0.f, 0.f};
#pragma unroll
        for (int kt = 0; kt < 4; kt++){
          bf16x8 a = *(const bf16x8*)(&sQ[mt*16 + tr][kt*32 + quad*8]);
          bf16x8 b2 = *(const bf16x8*)(&sK[lwave*16 + tr][kt*32 + quad*8]);
          sacc = __builtin_amdgcn_mfma_f32_16x16x32_bf16(a, b2, sacc, 0, 0, 0);
        }
        int colg = lwave * 16 + tr;
        float pr4[4];
#pragma unroll
        for (int r2 = 0; r2 < 4; r2++){
          float p = (colg < nkeys) ? __builtin_amdgcn_exp2f(sacc[r2] * K_EXP2) : 0.f;
          sP[mt*16 + quad*4 + r2][lwave*16 + tr] = f2bf(p);
          pr4[r2] = p;
        }
#pragma unroll
        for (int r2 = 0; r2 < 4; r2++){
          float ps = pr4[r2];
          ps += __shfl_xor(ps, 1, 64);
          ps += __shfl_xor(ps, 2, 64);
          ps += __shfl_xor(ps, 4, 64);
          ps += __shfl_xor(ps, 8, 64);
          if (tr == 0) atomicAdd(&sDen[mt*16 + quad*4 + r2], ps);
        }
      }
      __syncthreads();

#pragma unroll
      for (int mt = 0; mt < 3; mt++)
#pragma unroll
        for (int nt = 0; nt < 2; nt++)
#pragma unroll
          for (int kt = 0; kt < 2; kt++){
            bf16x8 a = *(const bf16x8*)(&sP[mt*16 + tr][kt*32 + quad*8]);
            bf16x8 b2 = *(const bf16x8*)(&sVt[lwave*32 + nt*16 + tr][kt*32 + quad*8]);
            acc[mt][nt] = __builtin_amdgcn_mfma_f32_16x16x32_bf16(a, b2, acc[mt][nt], 0, 0, 0);
          }
      __syncthreads();

#pragma unroll
      for (int mt = 0; mt < 3; mt++)
#pragma unroll
        for (int r2 = 0; r2 < 4; r2++){
          int row = mt*16 + quad*4 + r2;
          if (row < 45){
            float dinv = 1.0f / sDen[row];
            int hh = wi*5 + row/9, ww = wj*9 + row%9;
            size_t obase = ((size_t)((qf*40 + hh)*72 + ww)) * 512 + head * 128;
#pragma unroll
            for (int nt = 0; nt < 2; nt++){
              int col = lwave*32 + nt*16 + tr;
              yb[obase + col] = f2bf(acc[mt][nt][r2] * dinv);
            }
          }
        }
    }
  }
}

extern "C" void kernel_launch(void* const* d_in, const int* in_sizes, int n_in,
                              void* d_out, int out_size, void* d_ws, size_t ws_size,
                              hipStream_t stream)
{
  const float* x     = (const float*)d_in[0];
  const float* masks = (const float*)d_in[1];
  const float* Wq = (const float*)d_in[2];  const float* bq = (const float*)d_in[3];
  const float* Wk = (const float*)d_in[4];  const float* bk = (const float*)d_in[5];
  const float* Wv = (const float*)d_in[6];  const float* bv = (const float*)d_in[7];
  const float* Wp = (const float*)d_in[8];  const float* bp = (const float*)d_in[9];
  const float* pw = (const float*)d_in[10]; const float* pb = (const float*)d_in[11];
  float* out = (float*)d_out;

  char* ws = (char*)d_ws;
  size_t off = 0;
  auto alloc = [&](size_t bytes) -> char* {
    char* p = ws + off; off += (bytes + 255) & ~(size_t)255; return p;
  };
  // 18432 rows = 144*128 (token rows + pooled rows + padding for unguarded gload16 reads)
  u16* wt    = (u16*)alloc((size_t)4 * 512 * 512 * 2);
  u16* xbf   = (u16*)alloc((size_t)18432 * 512 * 2);
  u16* qbuf  = (u16*)alloc((size_t)18432 * 512 * 2);
  u16* kbuf  = (u16*)alloc((size_t)18432 * 512 * 2);
  u16* vbuf  = (u16*)alloc((size_t)18432 * 512 * 2);
  u16* ybuf  = (u16*)alloc((size_t)NTOK * 512 * 2);
  int* wmaskb = (int*)alloc(64 * 4);
  int* idxTabb = (int*)alloc((size_t)64 * 2240 * 4);

  u16* pkbuf = kbuf + (size_t)NTOK * 512;   // pooled K/V are tails of kbuf/vbuf
  u16* pvbuf = vbuf + (size_t)NTOK * 512;

  prep_all<<<dim3(11120), 256, 0, stream>>>(x, masks, Wq, Wk, Wv, Wp, pw, pb, xbf, wt, wmaskb, idxTabb);
  gemm_bias<<<dim3(144, 4, 3), 256, 0, stream>>>(xbf, wt, bq, bk, bv, qbuf, kbuf, vbuf, nullptr, 0, 1, 2, MALL);
  attn<<<dim3(64, 4), 512, 0, stream>>>(qbuf, kbuf, vbuf, pkbuf, pvbuf, wmaskb, idxTabb, ybuf);
  gemm_bias<<<dim3(135, 4, 1), 256, 0, stream>>>(ybuf, wt, bp, bp, bp, nullptr, nullptr, nullptr, out, 3, 3, 3, NTOK);
}

// Round 11
// 316.397 us; speedup vs baseline: 1.3618x; 1.0406x over previous
//
#include <hip/hip_runtime.h>

typedef unsigned short u16;
typedef unsigned int u32;
typedef __bf16 bf16x8 __attribute__((ext_vector_type(8)));
typedef float f32x4 __attribute__((ext_vector_type(4)));

#define TT 6
#define NTOK (6*40*72)      // 17280 tokens
#define NPOOL 1080          // pooled tokens (6 frames x 180)
#define MALL (NTOK + NPOOL) // 18360 rows through the QKV GEMM
#define KTOT 373            // keys per frame: 45 win + 148 rolled + 180 pooled
#define NKEYS (TT*KTOT)     // 2238 dense keys
#define NCH2 35             // ceil(2238/64) 64-key chunks
#define SCALE 0.08838834764831845f   // 1/sqrt(128)
#define K_EXP2 0.12751743f           // SCALE * log2(e): exp(s*SCALE) = exp2(s*K_EXP2)

__device__ __forceinline__ float bf2f(u16 u){ u32 x = ((u32)u) << 16; return __builtin_bit_cast(float, x); }
// native RNE f32->bf16 (compiler packs pairs into v_cvt_pk_bf16_f32)
__device__ __forceinline__ u16 f2bf(float f){ return __builtin_bit_cast(u16, (__bf16)f); }

// async global->LDS 16B/lane; LDS dest is wave-uniform base + lane*16 (pass the base)
__device__ __forceinline__ void gload16(const u16* g, u16* l){
  __builtin_amdgcn_global_load_lds(
      (const __attribute__((address_space(1))) void*)g,
      (__attribute__((address_space(3))) void*)l, 16, 0, 0);
}

// ---------------- MERGED PREP: convert_x | pool_conv | transpose_w | build_idx ----------------
// blocks [0,8640): convert x -> bf16 (4 elems/thread, exact cover)
// blocks [8640,10800): depthwise 4x4/4 pool conv -> bf16 rows appended at xbf+NTOK*512
// blocks [10800,11056): weight transpose (LDS-tiled)
// blocks [11056,11120): per-window wmask + gather table
__global__ __launch_bounds__(256) void prep_all(
    const float* __restrict__ x, const float* __restrict__ masks,
    const float* __restrict__ w0, const float* __restrict__ w1,
    const float* __restrict__ w2, const float* __restrict__ w3,
    const float* __restrict__ pw, const float* __restrict__ pb,
    u16* __restrict__ xbf, u16* __restrict__ wt,
    int* __restrict__ wmask, int* __restrict__ idxTab)
{
  __shared__ __align__(16) float tile[64][65];
  int b = blockIdx.x, tid = threadIdx.x;

  if (b < 8640){
    // ---- convert_x ----
    int i = b * 256 + tid;                     // 8640*256*4 == NTOK*512 exactly
    float4 v = *(const float4*)(x + (size_t)i * 4);
    u16 o[4] = {f2bf(v.x), f2bf(v.y), f2bf(v.z), f2bf(v.w)};
    *(uint2*)(xbf + (size_t)i * 4) = *(const uint2*)o;
  } else if (b < 10800){
    // ---- pool_conv ----
    int idx = (b - 8640) * 256 + tid;          // 2160*256 == 1080*512 exactly
    int c = idx & 511, n = idx >> 9;
    int f = n / 180, rp = n % 180, ph = rp / 18, pwc = rp % 18;
    float acc = pb[c];
#pragma unroll
    for (int i = 0; i < 4; i++)
#pragma unroll
      for (int j = 0; j < 4; j++){
        int hh = ph*4 + i, ww = pwc*4 + j;
        acc += x[((size_t)((f*40 + hh)*72 + ww)) * 512 + c] * pw[(i*4 + j)*512 + c];
      }
    xbf[(size_t)NTOK * 512 + idx] = f2bf(acc);
  } else if (b < 11056){
    // ---- transpose_w ----
    int idx = b - 10800;
    int m = idx >> 6, r = idx & 63;
    int kb = (r >> 3) * 64, nb = (r & 7) * 64;
    const float* src = m == 0 ? w0 : (m == 1 ? w1 : (m == 2 ? w2 : w3));
    int tx = tid & 63, ty = tid >> 6;          // 64 x 4
#pragma unroll
    for (int i = 0; i < 16; i++)
      tile[ty + 4*i][tx] = src[(size_t)(kb + ty + 4*i) * 512 + nb + tx];
    __syncthreads();
#pragma unroll
    for (int i = 0; i < 16; i++)
      wt[m * 262144 + (size_t)(nb + ty + 4*i) * 512 + kb + tx] = f2bf(tile[tx][ty + 4*i]);
  } else {
    // ---- build_idx (wmask + gather table; VALID_IND computed in-block) ----
    int* sVI = (int*)&tile[0][0];
    int* sFlag = sVI + 160;
    int win = b - 11056, wi = win >> 3, wj = win & 7;
    if (tid == 0){
      sFlag[0] = 0;
      int cnt = 0;
      for (int e = 0; e < 180; e++){
        int s = e / 45, pos = e % 45, pr = pos / 9, pc = pos % 9;
        bool inval = (s == 0 && pr < 2 && pc < 4) || (s == 1 && pr < 2 && pc >= 5) ||
                     (s == 2 && pr >= 3 && pc < 4) || (s == 3 && pr >= 3 && pc >= 5);
        if (!inval) sVI[cnt++] = e;
      }
    }
    __syncthreads();
    if (tid < 270){
      int f = tid / 45, p = tid - (tid / 45) * 45;
      int hh = wi*5 + p/9, ww = wj*9 + p%9;
      if (masks[(f*40 + hh)*72 + ww] > 0.f) atomicOr(sFlag, 1);
    }
    __syncthreads();
    if (tid == 0) wmask[win] = sFlag[0];

    for (int i = tid; i < NKEYS; i += 256){
      int f = i / KTOT, slot = i - f * KTOT;
      int idx;
      if (slot < 45){
        int hh = wi*5 + slot/9, ww = wj*9 + slot%9;
        idx = ((f*40 + hh)*72 + ww) * 1024;
      } else if (slot < 193){
        int e = sVI[slot - 45];
        int s2 = e / 45, pos = e - s2*45, pr = pos/9, pc = pos - pr*9;
        int hh = wi*5 + pr + ((s2 < 2) ? 3 : -3);
        int ww = wj*9 + pc + ((s2 & 1) ? -5 : 5);
        if (hh < 0) hh += 40; else if (hh >= 40) hh -= 40;
        if (ww < 0) ww += 72; else if (ww >= 72) ww -= 72;
        idx = ((f*40 + hh)*72 + ww) * 1024;
      } else {
        idx = ~((f*180 + (slot - 193)) * 1024);
      }
      idxTab[win * 2240 + i] = idx;
    }
  }
}

// ---------------- GEMM: C[M][512] = A[M][512] @ W + bias (BK=64, gload16 staging) ----------------
// 128x128 tile, BK=64: 8 k-steps, 16 barriers (half of BK=32), 32 MFMA/wave per barrier pair.
// LDS linear [128][64] u16 (32 KB total, 5 blocks/CU). Row stride 128B ≡ 0 mod 32 banks ->
// swizzle REQUIRED: global source seg = (lane&7)^(lane>>3) (write side stays linear for
// global_load_lds), read seg = (kt*4+quad)^(tr&7) -> 2 lanes/bank (free, m136).
__global__ __launch_bounds__(256) void gemm_bias(
    const u16* __restrict__ A, const u16* __restrict__ wt,
    const float* __restrict__ b0, const float* __restrict__ b1, const float* __restrict__ b2,
    u16* __restrict__ c0, u16* __restrict__ c1, u16* __restrict__ c2, float* __restrict__ cf,
    int wo0, int wo1, int wo2, int M)
{
  __shared__ __align__(16) u16 sA[128*64];
  __shared__ __align__(16) u16 sB[128*64];
  int z = blockIdx.z;
  const u16* Bt = wt + (size_t)(z == 0 ? wo0 : (z == 1 ? wo1 : wo2)) * 262144;
  const float* bias = z == 0 ? b0 : (z == 1 ? b1 : b2);
  u16* Cout = z == 0 ? c0 : (z == 1 ? c1 : c2);
  int mbase = blockIdx.x * 128, nbase = blockIdx.y * 128;
  int tid = threadIdx.x, lane = tid & 63, wave = tid >> 6;
  int wm = (wave >> 1) * 64, wn = (wave & 1) * 64;
  int quad = lane >> 4, tr = lane & 15;
  int lrow8 = lane >> 3;                       // 0..7: row within an 8-row wave staging group
  int seg   = (lane & 7) ^ lrow8;              // pre-swizzled global 16B segment (8 segs/row)

  // 4 staging calls per matrix per k-step; call r covers rows [r*32, r*32+32), wave w rows +w*8
  const u16* gA[4]; const u16* gB[4];
  u16* lA[4]; u16* lB[4];
#pragma unroll
  for (int r = 0; r < 4; r++){
    int row = r*32 + wave*8 + lrow8;
    gA[r] = A  + (size_t)(mbase + row) * 512 + seg*8;
    gB[r] = Bt + (size_t)(nbase + row) * 512 + seg*8;
    lA[r] = &sA[(r*32 + wave*8) * 64];
    lB[r] = &sB[(r*32 + wave*8) * 64];
  }

  f32x4 acc[4][4];
#pragma unroll
  for (int i = 0; i < 4; i++)
#pragma unroll
    for (int j = 0; j < 4; j++){ acc[i][j][0]=0.f; acc[i][j][1]=0.f; acc[i][j][2]=0.f; acc[i][j][3]=0.f; }

  for (int k0 = 0; k0 < 512; k0 += 64){
    if (k0) __syncthreads();                   // prev MFMA reads done
#pragma unroll
    for (int r = 0; r < 4; r++){
      gload16(gA[r] + k0, lA[r]);
      gload16(gB[r] + k0, lB[r]);
    }
    __syncthreads();                           // staged (vmcnt drained before barrier)
#pragma unroll
    for (int kt = 0; kt < 2; kt++){
      int rc = ((kt*4 + quad) ^ (tr & 7)) * 8; // swizzled read column (u16)
      bf16x8 a[4], b[4];
#pragma unroll
      for (int i = 0; i < 4; i++) a[i] = *(const bf16x8*)(&sA[(wm + i*16 + tr)*64 + rc]);
#pragma unroll
      for (int j = 0; j < 4; j++) b[j] = *(const bf16x8*)(&sB[(wn + j*16 + tr)*64 + rc]);
#pragma unroll
      for (int i = 0; i < 4; i++)
#pragma unroll
        for (int j = 0; j < 4; j++)
          acc[i][j] = __builtin_amdgcn_mfma_f32_16x16x32_bf16(a[i], b[j], acc[i][j], 0, 0, 0);
    }
  }

#pragma unroll
  for (int j = 0; j < 4; j++){
    int col = nbase + wn + j*16 + tr;
    float bv = bias[col];
#pragma unroll
    for (int i = 0; i < 4; i++)
#pragma unroll
      for (int r2 = 0; r2 < 4; r2++){
        int row = mbase + wm + i*16 + quad*4 + r2;
        if (row < M){
          float val = acc[i][j][r2] + bv;
          if (cf) cf[(size_t)row * 512 + col] = val;
          else    Cout[(size_t)row * 512 + col] = f2bf(val);
        }
      }
  }
}

// ---------------- local-window key address helper ----------------
__device__ __forceinline__ const u16* key_src_local(int slot, int qf, int wi, int wj, int head,
    const u16* __restrict__ tokbuf)
{
  int hh = wi*5 + slot/9, ww = wj*9 + slot%9;
  return tokbuf + ((size_t)((qf*40 + hh)*72 + ww)) * 512 + head * 128;
}

// ================= MERGED attention: block = (window, head), 512 threads =================
// Dense windows: swapped QK^T, packed P, 64-key chunks (proven round-7/9 body).
// Local windows: per-frame 45-key attention, 2 frames concurrently (waves 0-3 | 4-7).
__global__ __launch_bounds__(512) void attn(
    const u16* __restrict__ qb, const u16* __restrict__ kb, const u16* __restrict__ vb,
    const u16* __restrict__ pkb, const u16* __restrict__ pvb,
    const int* __restrict__ wmaskp, const int* __restrict__ idxTab,
    u16* __restrict__ yb)
{
  __shared__ __align__(16) char smem[112000];
  int win = blockIdx.x, head = blockIdx.y;
  int wi = win >> 3, wj = win & 7;
  int tid = threadIdx.x, lane = tid & 63, wave = tid >> 6;
  int quad = lane >> 4, tr = lane & 15;

  if (wmaskp[win]){
    // =============== DENSE path (LDS: 86400 B) ===============
    u16 (*sK)[136] = (u16(*)[136])smem;            // 64x136 u16
    u16 (*sVt)[72] = (u16(*)[72])(smem + 17408);   // 128x72 u16
    u32 (*sPw)[36] = (u32(*)[36])(smem + 35840);   // 288x36 u32
    int*  sIdx     = (int*)(smem + 77312);         // 2240
    float* sDenX   = (float*)(smem + 86272);       // 32

    if (tid < 32) sDenX[tid] = 0.f;
    {
      const int* g = idxTab + win * 2240;
      for (int i = tid; i < NKEYS; i += 512) sIdx[i] = g[i];
    }

    // ---- Q fragments in registers: own tiles 2w,2w+1 + shared tile 16+(w>>2) ----
    int mts[3] = {2*wave, 2*wave + 1, 16 + (wave >> 2)};
    bf16x8 qf[3][4];
#pragma unroll
    for (int im = 0; im < 3; im++){
      int row = mts[im]*16 + tr;
      int f = row / 48, r = row - f*48;
      bool vld = r < 45;
      int hh = wi*5 + r/9, ww = wj*9 + r%9;
      const u16* qp = qb + ((size_t)((f*40 + hh)*72 + ww))*512 + head*128;
#pragma unroll
      for (int kt = 0; kt < 4; kt++){
        uint4 v = make_uint4(0,0,0,0);
        if (vld) v = *(const uint4*)(qp + kt*32 + quad*8);
        qf[im][kt] = __builtin_bit_cast(bf16x8, v);
      }
    }

    f32x4 accv[2][8], accx[2];
#pragma unroll
    for (int m = 0; m < 2; m++)
#pragma unroll
      for (int nt = 0; nt < 8; nt++){ accv[m][nt][0]=0.f; accv[m][nt][1]=0.f; accv[m][nt][2]=0.f; accv[m][nt][3]=0.f; }
    accx[0][0]=0.f; accx[0][1]=0.f; accx[0][2]=0.f; accx[0][3]=0.f;
    accx[1][0]=0.f; accx[1][1]=0.f; accx[1][2]=0.f; accx[1][3]=0.f;
    float dacc[2] = {0.f, 0.f};
    float daccx = 0.f;

    __syncthreads();   // sIdx ready

    int upair = tid & 31, dgv = tid >> 5;
    const char* kb2  = (const char*)kb  + head*256 + (tid & 15)*16;
    const char* pkb2 = (const char*)pkb + head*256 + (tid & 15)*16;
    const char* vb2  = (const char*)vb  + head*256 + dgv*16;
    const char* pvb2 = (const char*)pvb + head*256 + dgv*16;

    uint4 pfk[2], pfv[2];
    auto pref = [&](int ch){
#pragma unroll
      for (int r = 0; r < 2; r++){ pfk[r] = make_uint4(0,0,0,0); pfv[r] = make_uint4(0,0,0,0); }
      if (ch < NCH2){
        int base = ch * 64;
#pragma unroll
        for (int r = 0; r < 2; r++){
          int jg = base + (tid >> 4) + 32*r;
          if (jg < NKEYS){
            int off = sIdx[jg];
            pfk[r] = *(const uint4*)(off >= 0 ? kb2 + off : pkb2 + ~off);
          }
        }
#pragma unroll
        for (int r = 0; r < 2; r++){
          int jg = base + 2*upair + r;
          if (jg < NKEYS){
            int off = sIdx[jg];
            pfv[r] = *(const uint4*)(off >= 0 ? vb2 + off : pvb2 + ~off);
          }
        }
      }
    };
    pref(0);

    for (int ch = 0; ch < NCH2; ch++){
      __syncthreads();               // prev PV done; sK/sVt free
#pragma unroll
      for (int r = 0; r < 2; r++)
        *(uint4*)(&sK[(tid >> 4) + 32*r][(tid & 15)*8]) = pfk[r];
      {
        u32 va[4] = {pfv[0].x, pfv[0].y, pfv[0].z, pfv[0].w};
        u32 vbp[4] = {pfv[1].x, pfv[1].y, pfv[1].z, pfv[1].w};
#pragma unroll
        for (int jj = 0; jj < 8; jj++){
          u32 lo = (va[jj >> 1] >> (16*(jj & 1))) & 0xffffu;
          u32 hi = (vbp[jj >> 1] >> (16*(jj & 1))) & 0xffffu;
          ((u32*)&sVt[dgv*8 + jj][0])[upair] = lo | (hi << 16);
        }
      }
      __syncthreads();               // staged
      pref(ch + 1);                  // overlap next gather with compute

      // ---- QK^T (swapped: S^T) + exp + packed P store ----
#pragma unroll
      for (int nt = 0; nt < 4; nt++){
        bf16x8 bk[4];
#pragma unroll
        for (int kt = 0; kt < 4; kt++) bk[kt] = *(const bf16x8*)(&sK[nt*16 + tr][kt*32 + quad*8]);
        int colb = ch*64 + nt*16 + quad*4;
#pragma unroll
        for (int m = 0; m < 2; m++){
          f32x4 s = {0.f, 0.f, 0.f, 0.f};
#pragma unroll
          for (int kt = 0; kt < 4; kt++) s = __builtin_amdgcn_mfma_f32_16x16x32_bf16(bk[kt], qf[m][kt], s, 0, 0, 0);
          float p[4];
#pragma unroll
          for (int r2 = 0; r2 < 4; r2++){
            p[r2] = (colb + r2 < NKEYS) ? __builtin_amdgcn_exp2f(s[r2] * K_EXP2) : 0.f;
            dacc[m] += p[r2];
          }
          uint2 w;
          w.x = (u32)f2bf(p[0]) | ((u32)f2bf(p[1]) << 16);
          w.y = (u32)f2bf(p[2]) | ((u32)f2bf(p[3]) << 16);
          *(uint2*)(&sPw[(2*wave + m)*16 + tr][nt*8 + quad*2]) = w;
        }
        if (nt == (wave & 3)){
          f32x4 s = {0.f, 0.f, 0.f, 0.f};
#pragma unroll
          for (int kt = 0; kt < 4; kt++) s = __builtin_amdgcn_mfma_f32_16x16x32_bf16(bk[kt], qf[2][kt], s, 0, 0, 0);
          float p[4];
#pragma unroll
          for (int r2 = 0; r2 < 4; r2++){
            p[r2] = (colb + r2 < NKEYS) ? __builtin_amdgcn_exp2f(s[r2] * K_EXP2) : 0.f;
            daccx += p[r2];
          }
          uint2 w;
          w.x = (u32)f2bf(p[0]) | ((u32)f2bf(p[1]) << 16);
          w.y = (u32)f2bf(p[2]) | ((u32)f2bf(p[3]) << 16);
          *(uint2*)(&sPw[(16 + (wave >> 2))*16 + tr][nt*8 + quad*2]) = w;
        }
      }
      __syncthreads();               // sPw complete

      // ---- PV (64 keys = 2 k-steps) ----
#pragma unroll
      for (int kt2 = 0; kt2 < 2; kt2++){
        bf16x8 a0 = *(const bf16x8*)(&sPw[(2*wave)*16 + tr][kt2*16 + quad*4]);
        bf16x8 a1 = *(const bf16x8*)(&sPw[(2*wave + 1)*16 + tr][kt2*16 + quad*4]);
        bf16x8 ax = *(const bf16x8*)(&sPw[(16 + (wave >> 2))*16 + tr][kt2*16 + quad*4]);
#pragma unroll
        for (int nt = 0; nt < 8; nt++){
          bf16x8 bv = *(const bf16x8*)(&sVt[nt*16 + tr][kt2*32 + quad*8]);
          accv[0][nt] = __builtin_amdgcn_mfma_f32_16x16x32_bf16(a0, bv, accv[0][nt], 0, 0, 0);
          accv[1][nt] = __builtin_amdgcn_mfma_f32_16x16x32_bf16(a1, bv, accv[1][nt], 0, 0, 0);
        }
        int he0 = (wave & 3)*2;
        bf16x8 bx0 = *(const bf16x8*)(&sVt[he0*16 + tr][kt2*32 + quad*8]);
        bf16x8 bx1 = *(const bf16x8*)(&sVt[(he0+1)*16 + tr][kt2*32 + quad*8]);
        accx[0] = __builtin_amdgcn_mfma_f32_16x16x32_bf16(ax, bx0, accx[0], 0, 0, 0);
        accx[1] = __builtin_amdgcn_mfma_f32_16x16x32_bf16(ax, bx1, accx[1], 0, 0, 0);
      }
    }

    // ---- denominators ----
    float dred[2];
#pragma unroll
    for (int m = 0; m < 2; m++){
      float d = dacc[m];
      d += __shfl_xor(d, 16, 64); d += __shfl_xor(d, 32, 64);
      dred[m] = d;
    }
    {
      float d = daccx;
      d += __shfl_xor(d, 16, 64); d += __shfl_xor(d, 32, 64);
      if (lane < 16) atomicAdd(&sDenX[(wave >> 2)*16 + lane], d);
    }
    __syncthreads();

    // ---- epilogue: own tiles ----
#pragma unroll
    for (int m = 0; m < 2; m++){
#pragma unroll
      for (int r2 = 0; r2 < 4; r2++){
        float dinvv = 1.f / __shfl(dred[m], quad*4 + r2, 64);
        int row = (2*wave + m)*16 + quad*4 + r2;
        int f = row / 48, r = row - f*48;
        if (r < 45){
          int hh = wi*5 + r/9, ww = wj*9 + r%9;
          size_t base = ((size_t)((f*40 + hh)*72 + ww))*512 + head*128;
#pragma unroll
          for (int nt = 0; nt < 8; nt++)
            yb[base + nt*16 + tr] = f2bf(accv[m][nt][r2] * dinvv);
        }
      }
    }
    // ---- epilogue: shared tile ----
    {
      int e = 16 + (wave >> 2), he0 = (wave & 3)*2;
#pragma unroll
      for (int r2 = 0; r2 < 4; r2++){
        int row = e*16 + quad*4 + r2;
        int f = row / 48, r = row - f*48;
        if (r < 45){
          float dinvv = 1.f / sDenX[(e - 16)*16 + quad*4 + r2];
          int hh = wi*5 + r/9, ww = wj*9 + r%9;
          size_t base = ((size_t)((f*40 + hh)*72 + ww))*512 + head*128;
          yb[base + he0*16 + tr]       = f2bf(accx[0][r2] * dinvv);
          yb[base + (he0 + 1)*16 + tr] = f2bf(accx[1][r2] * dinvv);
        }
      }
    }
  } else {
    // =============== LOCAL path: 2 frames concurrently (56000 B LDS per half) ===============
    int half = wave >> 2, lwave = wave & 3, ltid = tid & 255;
    char* base = smem + half * 56000;
    u16 (*sQ)[136]  = (u16(*)[136])base;            // 48x136
    u16 (*sK)[136]  = (u16(*)[136])(base + 13056);  // 64x136
    u16 (*sVt)[72]  = (u16(*)[72])(base + 30464);   // 128x72
    u16 (*sP)[72]   = (u16(*)[72])(base + 48896);   // 48x72
    float* sDen     = (float*)(base + 55808);       // 48
    const int nkeys = 45;

    for (int it = 0; it < 3; it++){
      int qf = it*2 + half;
      if (it) __syncthreads();                 // prev epilogue done before re-staging
      if (ltid < 48) sDen[ltid] = 0.f;

      // stage Q
#pragma unroll
      for (int r = 0; r < 3; r++){
        int u = ltid + 256 * r;
        int row = u >> 4, dg = u & 15;
        uint4 val = make_uint4(0,0,0,0);
        if (row < 45){
          int hh = wi*5 + row/9, ww = wj*9 + row%9;
          val = *(const uint4*)(qb + ((size_t)((qf*40 + hh)*72 + ww)) * 512 + head*128 + dg*8);
        }
        *(uint4*)(&sQ[row][dg * 8]) = val;
      }

      f32x4 acc[3][2];
#pragma unroll
      for (int a = 0; a < 3; a++)
#pragma unroll
        for (int b2 = 0; b2 < 2; b2++){ acc[a][b2][0]=0.f; acc[a][b2][1]=0.f; acc[a][b2][2]=0.f; acc[a][b2][3]=0.f; }

      // stage K (coalesced) and V (transposed)
#pragma unroll
      for (int r = 0; r < 4; r++){
        int u = ltid + 256 * r;
        int key = u >> 4, dg = u & 15;
        uint4 val = make_uint4(0,0,0,0);
        if (key < nkeys) val = *(const uint4*)(key_src_local(key, qf, wi, wj, head, kb) + dg * 8);
        *(uint4*)(&sK[key][dg * 8]) = val;
      }
#pragma unroll
      for (int r = 0; r < 4; r++){
        int u = ltid + 256 * r;
        int key = u & 63, dg = u >> 6;
        uint4 val = make_uint4(0,0,0,0);
        if (key < nkeys) val = *(const uint4*)(key_src_local(key, qf, wi, wj, head, vb) + dg * 8);
        u32 vv[4] = {val.x, val.y, val.z, val.w};
#pragma unroll
        for (int q2 = 0; q2 < 4; q2++){
          sVt[dg*8 + q2*2][key]     = (u16)(vv[q2] & 0xffff);
          sVt[dg*8 + q2*2 + 1][key] = (u16)(vv[q2] >> 16);
        }
      }
      __syncthreads();

#pragma unroll
      for (int mt = 0; mt < 3; mt++){
        f32x4 sacc = {0.f, 0.f, 0.f, 0.f};
#pragma unroll
        for (int kt = 0; kt < 4; kt++){
          bf16x8 a = *(const bf16x8*)(&sQ[mt*16 + tr][kt*32 + quad*8]);
          bf16x8 b2 = *(const bf16x8*)(&sK[lwave*16 + tr][kt*32 + quad*8]);
          sacc = __builtin_amdgcn_mfma_f32_16x16x32_bf16(a, b2, sacc, 0, 0, 0);
        }
        int colg = lwave * 16 + tr;
        float pr4[4];
#pragma unroll
        for (int r2 = 0; r2 < 4; r2++){
          float p = (colg < nkeys) ? __builtin_amdgcn_exp2f(sacc[r2] * K_EXP2) : 0.f;
          sP[mt*16 + quad*4 + r2][lwave*16 + tr] = f2bf(p);
          pr4[r2] = p;
        }
#pragma unroll
        for (int r2 = 0; r2 < 4; r2++){
          float ps = pr4[r2];
          ps += __shfl_xor(ps, 1, 64);
          ps += __shfl_xor(ps, 2, 64);
          ps += __shfl_xor(ps, 4, 64);
          ps += __shfl_xor(ps, 8, 64);
          if (tr == 0) atomicAdd(&sDen[mt*16 + quad*4 + r2], ps);
        }
      }
      __syncthreads();

#pragma unroll
      for (int mt = 0; mt < 3; mt++)
#pragma unroll
        for (int nt = 0; nt < 2; nt++)
#pragma unroll
          for (int kt = 0; kt < 2; kt++){
            bf16x8 a = *(const bf16x8*)(&sP[mt*16 + tr][kt*32 + quad*8]);
            bf16x8 b2 = *(const bf16x8*)(&sVt[lwave*32 + nt*16 + tr][kt*32 + quad*8]);
            acc[mt][nt] = __builtin_amdgcn_mfma_f32_16x16x32_bf16(a, b2, acc[mt][nt], 0, 0, 0);
          }
      __syncthreads();

#pragma unroll
      for (int mt = 0; mt < 3; mt++)
#pragma unroll
        for (int r2 = 0; r2 < 4; r2++){
          int row = mt*16 + quad*4 + r2;
          if (row < 45){
            float dinv = 1.0f / sDen[row];
            int hh = wi*5 + row/9, ww = wj*9 + row%9;
            size_t obase = ((size_t)((qf*40 + hh)*72 + ww)) * 512 + head * 128;
#pragma unroll
            for (int nt = 0; nt < 2; nt++){
              int col = lwave*32 + nt*16 + tr;
              yb[obase + col] = f2bf(acc[mt][nt][r2] * dinv);
            }
          }
        }
    }
  }
}

extern "C" void kernel_launch(void* const* d_in, const int* in_sizes, int n_in,
                              void* d_out, int out_size, void* d_ws, size_t ws_size,
                              hipStream_t stream)
{
  const float* x     = (const float*)d_in[0];
  const float* masks = (const float*)d_in[1];
  const float* Wq = (const float*)d_in[2];  const float* bq = (const float*)d_in[3];
  const float* Wk = (const float*)d_in[4];  const float* bk = (const float*)d_in[5];
  const float* Wv = (const float*)d_in[6];  const float* bv = (const float*)d_in[7];
  const float* Wp = (const float*)d_in[8];  const float* bp = (const float*)d_in[9];
  const float* pw = (const float*)d_in[10]; const float* pb = (const float*)d_in[11];
  float* out = (float*)d_out;

  char* ws = (char*)d_ws;
  size_t off = 0;
  auto alloc = [&](size_t bytes) -> char* {
    char* p = ws + off; off += (bytes + 255) & ~(size_t)255; return p;
  };
  // 18432 rows = 144*128 (token rows + pooled rows + padding for unguarded gload16 reads)
  u16* wt    = (u16*)alloc((size_t)4 * 512 * 512 * 2);
  u16* xbf   = (u16*)alloc((size_t)18432 * 512 * 2);
  u16* qbuf  = (u16*)alloc((size_t)18432 * 512 * 2);
  u16* kbuf  = (u16*)alloc((size_t)18432 * 512 * 2);
  u16* vbuf  = (u16*)alloc((size_t)18432 * 512 * 2);
  u16* ybuf  = (u16*)alloc((size_t)NTOK * 512 * 2);
  int* wmaskb = (int*)alloc(64 * 4);
  int* idxTabb = (int*)alloc((size_t)64 * 2240 * 4);

  u16* pkbuf = kbuf + (size_t)NTOK * 512;   // pooled K/V are tails of kbuf/vbuf
  u16* pvbuf = vbuf + (size_t)NTOK * 512;

  prep_all<<<dim3(11120), 256, 0, stream>>>(x, masks, Wq, Wk, Wv, Wp, pw, pb, xbf, wt, wmaskb, idxTabb);
  gemm_bias<<<dim3(144, 4, 3), 256, 0, stream>>>(xbf, wt, bq, bk, bv, qbuf, kbuf, vbuf, nullptr, 0, 1, 2, MALL);
  attn<<<dim3(64, 4), 512, 0, stream>>>(qbuf, kbuf, vbuf, pkbuf, pvbuf, wmaskb, idxTabb, ybuf);
  gemm_bias<<<dim3(135, 4, 1), 256, 0, stream>>>(ybuf, wt, bp, bp, bp, nullptr, nullptr, nullptr, out, 3, 3, 3, NTOK);
}